// Round 1
// baseline (823.099 us; speedup 1.0000x reference)
//
#include <hip/hip_runtime.h>
#include <math.h>

// ---------------- graph prep ----------------

__global__ void k_degree(const int* __restrict__ dst, int* __restrict__ degi, int E) {
  int e = blockIdx.x * blockDim.x + threadIdx.x;
  if (e < E) atomicAdd(&degi[dst[e]], 1);
}

__global__ void k_dinv(const int* __restrict__ degi, float* __restrict__ dinv, int n) {
  int i = blockIdx.x * blockDim.x + threadIdx.x;
  if (i < n) dinv[i] = rsqrtf((float)(degi[i] + 1));  // +1 self-loop
}

__global__ __launch_bounds__(1024)
void k_scan(const int* __restrict__ deg, int* __restrict__ off, int n) {
  __shared__ int lds[1024];
  __shared__ int carry_s;
  int tid = threadIdx.x;
  if (tid == 0) carry_s = 0;
  __syncthreads();
  for (int base = 0; base < n; base += 1024) {
    int i = base + tid;
    int v = (i < n) ? deg[i] : 0;
    lds[tid] = v;
    __syncthreads();
    for (int s = 1; s < 1024; s <<= 1) {
      int t = (tid >= s) ? lds[tid - s] : 0;
      __syncthreads();
      lds[tid] += t;
      __syncthreads();
    }
    int carry = carry_s;
    if (i < n) off[i] = carry + lds[tid] - v;   // exclusive
    __syncthreads();
    if (tid == 0) carry_s = carry + lds[1023];
    __syncthreads();
  }
  if (tid == 0) off[n] = carry_s;
}

__global__ void k_scatter(const int* __restrict__ srcv, const int* __restrict__ dstv,
                          const float* __restrict__ dinv, const int* __restrict__ off,
                          int* __restrict__ cursor, int* __restrict__ csr_src,
                          float* __restrict__ csr_norm, int E) {
  int e = blockIdx.x * blockDim.x + threadIdx.x;
  if (e >= E) return;
  int d = dstv[e];
  int p = atomicAdd(&cursor[d], 1);
  int slot = off[d] + p;
  int s = srcv[e];
  csr_src[slot] = s;
  csr_norm[slot] = dinv[s] * dinv[d];
}

// ---------------- GEMM: [nrows,128] x [128,128] ----------------
// block 256 threads, 16 rows/block; A tile in LDS, W streamed (L1/L2-hot)

__global__ __launch_bounds__(256)
void k_gemm128(const float* __restrict__ A, const float* __restrict__ W,
               float* __restrict__ out, int nrows) {
  __shared__ float a[16][128];
  int tid = threadIdx.x;
  long r0 = (long)blockIdx.x * 16;
  {
    const float4* A4 = (const float4*)(A + r0 * 128);
    float4* a4 = (float4*)&a[0][0];
#pragma unroll
    for (int i = 0; i < 2; ++i) {
      int idx = tid + i * 256;
      if (r0 * 128 + (long)idx * 4 < (long)nrows * 128) a4[idx] = A4[idx];
      else a4[idx] = make_float4(0.f, 0.f, 0.f, 0.f);
    }
  }
  __syncthreads();
  int col = tid & 127;
  int rb = (tid >> 7) * 8;
  float acc[8] = {};
  for (int k = 0; k < 128; k += 4) {
    float w0 = W[(k + 0) * 128 + col];
    float w1 = W[(k + 1) * 128 + col];
    float w2 = W[(k + 2) * 128 + col];
    float w3 = W[(k + 3) * 128 + col];
#pragma unroll
    for (int i = 0; i < 8; ++i) {
      float4 av = *(const float4*)&a[rb + i][k];
      acc[i] += av.x * w0 + av.y * w1 + av.z * w2 + av.w * w3;
    }
  }
#pragma unroll
  for (int i = 0; i < 8; ++i) {
    long r = r0 + rb + i;
    if (r < nrows) out[r * 128 + col] = acc[i];
  }
}

// ---------------- GCN aggregate + bias + ReLU + LN + residual ----------------
// one block (128 threads) per node

__global__ __launch_bounds__(128)
void k_aggregate(const float* __restrict__ hw, const int* __restrict__ off,
                 const int* __restrict__ csr_src, const float* __restrict__ csr_norm,
                 const float* __restrict__ dinv, const float* __restrict__ bias,
                 const float* __restrict__ ln_g, const float* __restrict__ ln_b,
                 const float* __restrict__ prev, float* __restrict__ outp) {
  int node = blockIdx.x;
  int tid = threadIdx.x;
  float dn = dinv[node];
  float acc = hw[(long)node * 128 + tid] * dn * dn;      // self loop
  int s0 = off[node], s1 = off[node + 1];
  for (int i = s0; i < s1; ++i) {
    int s = csr_src[i];
    acc += hw[(long)s * 128 + tid] * csr_norm[i];
  }
  acc += bias[tid];
  acc = fmaxf(acc, 0.f);
  // LayerNorm over 128 channels (2 waves)
  float sum = acc, sq = acc * acc;
#pragma unroll
  for (int m = 32; m; m >>= 1) { sum += __shfl_xor(sum, m); sq += __shfl_xor(sq, m); }
  __shared__ float ws0[2], ws1[2];
  if ((tid & 63) == 0) { ws0[tid >> 6] = sum; ws1[tid >> 6] = sq; }
  __syncthreads();
  sum = ws0[0] + ws0[1];
  sq  = ws1[0] + ws1[1];
  float mu = sum * (1.f / 128.f);
  float var = sq * (1.f / 128.f) - mu * mu;
  float v = (acc - mu) * rsqrtf(var + 1e-5f) * ln_g[tid] + ln_b[tid];
  outp[(long)node * 128 + tid] = prev[(long)node * 128 + tid] + v;
}

// ---------------- fused attention + LN + out-proj ----------------
// 8 nodes per block, 128 threads. Only l=2 query row is needed by the output.

__global__ __launch_bounds__(128)
void k_attention(const float* __restrict__ emb0, const float* __restrict__ emb1,
                 const float* __restrict__ emb2,
                 const float* __restrict__ wq, const float* __restrict__ wk,
                 const float* __restrict__ wv,
                 const float* __restrict__ ln_g, const float* __restrict__ ln_b,
                 const float* __restrict__ out_w, const float* __restrict__ out_b,
                 float* __restrict__ zout) {
  __shared__ float e[24][128];   // row r = l*8 + node ; reused as z[8][128] later
  __shared__ float kk[24][128];
  __shared__ float vv[24][128];
  __shared__ float qq[8][128];
  int tid = threadIdx.x;
  long nb = (long)blockIdx.x * 8;
  {
    const float4* s0 = (const float4*)(emb0 + nb * 128);
    const float4* s1 = (const float4*)(emb1 + nb * 128);
    const float4* s2 = (const float4*)(emb2 + nb * 128);
    float4* d0 = (float4*)&e[0][0];
    float4* d1 = (float4*)&e[8][0];
    float4* d2 = (float4*)&e[16][0];
#pragma unroll
    for (int i = 0; i < 2; ++i) {
      d0[tid + i * 128] = s0[tid + i * 128];
      d1[tid + i * 128] = s1[tid + i * 128];
      d2[tid + i * 128] = s2[tid + i * 128];
    }
  }
  __syncthreads();

  // K and V for all 24 rows (col = tid), fused to share LDS reads of e
  {
    float accK[24] = {};
    float accV[24] = {};
    for (int k = 0; k < 128; k += 4) {
      float k0 = wk[(k + 0) * 128 + tid], k1 = wk[(k + 1) * 128 + tid];
      float k2 = wk[(k + 2) * 128 + tid], k3 = wk[(k + 3) * 128 + tid];
      float v0 = wv[(k + 0) * 128 + tid], v1 = wv[(k + 1) * 128 + tid];
      float v2 = wv[(k + 2) * 128 + tid], v3 = wv[(k + 3) * 128 + tid];
#pragma unroll
      for (int r = 0; r < 24; ++r) {
        float4 av = *(const float4*)&e[r][k];
        accK[r] += av.x * k0 + av.y * k1 + av.z * k2 + av.w * k3;
        accV[r] += av.x * v0 + av.y * v1 + av.z * v2 + av.w * v3;
      }
    }
#pragma unroll
    for (int r = 0; r < 24; ++r) { kk[r][tid] = accK[r]; vv[r][tid] = accV[r]; }
  }
  // Q for l=2 rows only
  {
    float accQ[8] = {};
    for (int k = 0; k < 128; k += 4) {
      float q0 = wq[(k + 0) * 128 + tid], q1 = wq[(k + 1) * 128 + tid];
      float q2 = wq[(k + 2) * 128 + tid], q3 = wq[(k + 3) * 128 + tid];
#pragma unroll
      for (int r = 0; r < 8; ++r) {
        float4 av = *(const float4*)&e[16 + r][k];
        accQ[r] += av.x * q0 + av.y * q1 + av.z * q2 + av.w * q3;
      }
    }
#pragma unroll
    for (int r = 0; r < 8; ++r) qq[r][tid] = accQ[r];
  }
  __syncthreads();

  // attention math: thread -> (node = tid>>4, d = tid&15); 8 heads looped
  int node = tid >> 4;
  int d = tid & 15;
  float ctx[8];
#pragma unroll
  for (int h = 0; h < 8; ++h) {
    int c = h * 16 + d;
    float q = qq[node][c];
    float s[3];
#pragma unroll
    for (int m = 0; m < 3; ++m) {
      float p = q * kk[m * 8 + node][c];
      p += __shfl_xor(p, 1); p += __shfl_xor(p, 2);
      p += __shfl_xor(p, 4); p += __shfl_xor(p, 8);
      s[m] = p * 0.25f;   // /sqrt(16)
    }
    float mx = fmaxf(s[0], fmaxf(s[1], s[2]));
    float e0 = __expf(s[0] - mx), e1 = __expf(s[1] - mx), e2 = __expf(s[2] - mx);
    float inv = 1.f / (e0 + e1 + e2);
    ctx[h] = (e0 * vv[node][c] + e1 * vv[8 + node][c] + e2 * vv[16 + node][c]) * inv;
  }
  // LayerNorm over 128 channels of this node (8 per thread x 16 lanes)
  float sum = 0.f, sq = 0.f;
#pragma unroll
  for (int h = 0; h < 8; ++h) { sum += ctx[h]; sq += ctx[h] * ctx[h]; }
#pragma unroll
  for (int m = 1; m < 16; m <<= 1) { sum += __shfl_xor(sum, m); sq += __shfl_xor(sq, m); }
  float mu = sum * (1.f / 128.f);
  float var = sq * (1.f / 128.f) - mu * mu;
  float rs = rsqrtf(var + 1e-5f);
  float* z = &e[0][0];   // e no longer needed: reuse as z[8][128]
#pragma unroll
  for (int h = 0; h < 8; ++h) {
    int c = h * 16 + d;
    z[node * 128 + c] = (ctx[h] - mu) * rs * ln_g[c] + ln_b[c];
  }
  __syncthreads();

  // out projection: zout[nb+r][tid] = z[r] . out_w[:,tid] + out_b[tid]
  {
    float accO[8] = {};
    for (int k = 0; k < 128; k += 4) {
      float w0 = out_w[(k + 0) * 128 + tid], w1 = out_w[(k + 1) * 128 + tid];
      float w2 = out_w[(k + 2) * 128 + tid], w3 = out_w[(k + 3) * 128 + tid];
#pragma unroll
      for (int r = 0; r < 8; ++r) {
        float4 zv = *(const float4*)&z[r * 128 + k];
        accO[r] += zv.x * w0 + zv.y * w1 + zv.z * w2 + zv.w * w3;
      }
    }
    float ob = out_b[tid];
#pragma unroll
    for (int r = 0; r < 8; ++r) zout[(nb + r) * 128 + tid] = accO[r] + ob;
  }
}

// ---------------- gather rows ----------------

__global__ void k_gather(const float* __restrict__ zout, const int* __restrict__ ids,
                         float* __restrict__ outp, int rows) {
  int t = blockIdx.x * blockDim.x + threadIdx.x;  // one float4 per thread
  if (t >= rows * 32) return;
  int row = t >> 5, c4 = t & 31;
  long id = ids[row];
  ((float4*)outp)[(long)row * 32 + c4] = ((const float4*)zout)[id * 32 + c4];
}

// ---------------- host ----------------

extern "C" void kernel_launch(void* const* d_in, const int* in_sizes, int n_in,
                              void* d_out, int out_size, void* d_ws, size_t ws_size,
                              hipStream_t stream) {
  const float* x = (const float*)d_in[0];
  const int* ei = (const int*)d_in[1];
  const int* ids[4] = {(const int*)d_in[2], (const int*)d_in[3],
                       (const int*)d_in[4], (const int*)d_in[5]};
  const float* gw[3] = {(const float*)d_in[7], (const float*)d_in[9], (const float*)d_in[11]};
  const float* gb[3] = {(const float*)d_in[8], (const float*)d_in[10], (const float*)d_in[12]};
  const float* wq = (const float*)d_in[13];
  const float* wk = (const float*)d_in[14];
  const float* wv = (const float*)d_in[15];
  const float* ln_g = (const float*)d_in[16];
  const float* ln_b = (const float*)d_in[17];
  const float* out_w = (const float*)d_in[18];
  const float* out_b = (const float*)d_in[19];

  const int N = in_sizes[0] / 128;
  const int E = in_sizes[1] / 2;
  const int P = in_sizes[2];

  char* w = (char*)d_ws;
  size_t o = 0;
  auto take = [&](size_t bytes) -> void* {
    void* p = w + o;
    o = (o + bytes + 255) & ~(size_t)255;
    return p;
  };
  int*   degi    = (int*)take((size_t)N * 4);
  int*   off     = (int*)take((size_t)(N + 1) * 4);
  int*   cursor  = (int*)take((size_t)N * 4);
  float* dinv    = (float*)take((size_t)N * 4);
  int*   csr_src = (int*)take((size_t)E * 4);
  float* csr_nrm = (float*)take((size_t)E * 4);
  float* hw      = (float*)take((size_t)N * 128 * 4);   // also reused as zout
  float* emb0    = (float*)take((size_t)N * 128 * 4);
  float* emb1    = (float*)take((size_t)N * 128 * 4);
  float* emb2    = (float*)take((size_t)N * 128 * 4);
  (void)ws_size; (void)n_in; (void)out_size;

  hipMemsetAsync(degi, 0, (size_t)N * 4, stream);
  hipMemsetAsync(cursor, 0, (size_t)N * 4, stream);

  int eb = (E + 255) / 256;
  k_degree<<<eb, 256, 0, stream>>>(ei + E, degi, E);
  k_dinv<<<(N + 255) / 256, 256, 0, stream>>>(degi, dinv, N);
  k_scan<<<1, 1024, 0, stream>>>(degi, off, N);
  k_scatter<<<eb, 256, 0, stream>>>(ei, ei + E, dinv, off, cursor, csr_src, csr_nrm, E);

  const float* cur = x;
  float* embs[3] = {emb0, emb1, emb2};
  int gblocks = (N + 15) / 16;
  for (int l = 0; l < 3; ++l) {
    k_gemm128<<<gblocks, 256, 0, stream>>>(cur, gw[l], hw, N);
    k_aggregate<<<N, 128, 0, stream>>>(hw, off, csr_src, csr_nrm, dinv, gb[l],
                                       ln_g, ln_b, cur, embs[l]);
    cur = embs[l];
  }

  k_attention<<<N / 8, 128, 0, stream>>>(emb0, emb1, emb2, wq, wk, wv,
                                         ln_g, ln_b, out_w, out_b, hw);

  float* outf = (float*)d_out;
  int gb2 = (P * 32 + 255) / 256;
  for (int s = 0; s < 4; ++s)
    k_gather<<<gb2, 256, 0, stream>>>(hw, ids[s], outf + (size_t)s * P * 128, P);
}

// Round 2
// 498.424 us; speedup vs baseline: 1.6514x; 1.6514x over previous
//
#include <hip/hip_runtime.h>
#include <math.h>

using bf16x8 = __attribute__((ext_vector_type(8))) short;
using f32x4  = __attribute__((ext_vector_type(4))) float;

__device__ __forceinline__ unsigned short f2b(float f) {
  unsigned u = __float_as_uint(f);
  u += 0x7FFFu + ((u >> 16) & 1u);
  return (unsigned short)(u >> 16);
}
__device__ __forceinline__ float b2f(unsigned short h) {
  return __uint_as_float((unsigned)h << 16);
}
__device__ __forceinline__ float2 ldb2(const unsigned short* p) {
  unsigned u = *(const unsigned*)p;
  return make_float2(__uint_as_float(u << 16), __uint_as_float(u & 0xFFFF0000u));
}

// ---------------- graph prep ----------------

__global__ void k_degree(const int* __restrict__ dst, int* __restrict__ degi, int E) {
  int e = blockIdx.x * blockDim.x + threadIdx.x;
  if (e < E) atomicAdd(&degi[dst[e]], 1);
}

__global__ void k_dinv(const int* __restrict__ degi, float* __restrict__ dinv, int n) {
  int i = blockIdx.x * blockDim.x + threadIdx.x;
  if (i < n) dinv[i] = rsqrtf((float)(degi[i] + 1));  // +1 self-loop
}

// 3-phase exclusive scan of deg -> off (replaces single-block serial scan)
__global__ __launch_bounds__(256)
void k_part(const int* __restrict__ deg, int* __restrict__ part, int n) {
  __shared__ int l[256];
  int tid = threadIdx.x, i = blockIdx.x * 256 + tid;
  l[tid] = (i < n) ? deg[i] : 0;
  __syncthreads();
  for (int s = 128; s; s >>= 1) { if (tid < s) l[tid] += l[tid + s]; __syncthreads(); }
  if (!tid) part[blockIdx.x] = l[0];
}

__global__ __launch_bounds__(1024)
void k_scanpart(int* __restrict__ part, int np, int* __restrict__ off_n) {
  __shared__ int l[1024];
  int tid = threadIdx.x;
  int v = (tid < np) ? part[tid] : 0;
  l[tid] = v;
  __syncthreads();
  for (int s = 1; s < 1024; s <<= 1) {
    int t = (tid >= s) ? l[tid - s] : 0;
    __syncthreads();
    l[tid] += t;
    __syncthreads();
  }
  if (tid < np) part[tid] = l[tid] - v;   // exclusive
  if (tid == np - 1) *off_n = l[tid];     // total = E
}

__global__ __launch_bounds__(256)
void k_off(const int* __restrict__ deg, const int* __restrict__ part,
           int* __restrict__ off, int n) {
  __shared__ int l[256];
  int tid = threadIdx.x, i = blockIdx.x * 256 + tid;
  int v = (i < n) ? deg[i] : 0;
  l[tid] = v;
  __syncthreads();
  for (int s = 1; s < 256; s <<= 1) {
    int t = (tid >= s) ? l[tid - s] : 0;
    __syncthreads();
    l[tid] += t;
    __syncthreads();
  }
  if (i < n) off[i] = part[blockIdx.x] + l[tid] - v;
}

__global__ void k_scatter(const int* __restrict__ srcv, const int* __restrict__ dstv,
                          const float* __restrict__ dinv, const int* __restrict__ off,
                          int* __restrict__ cursor, int* __restrict__ csr_src,
                          float* __restrict__ csr_norm, int E) {
  int e = blockIdx.x * blockDim.x + threadIdx.x;
  if (e >= E) return;
  int d = dstv[e];
  int p = atomicAdd(&cursor[d], 1);
  int slot = off[d] + p;
  int s = srcv[e];
  csr_src[slot] = s;
  csr_norm[slot] = dinv[s] * dinv[d];
}

// ---------------- weight convert + transpose (fp32 [128,128] -> bf16 [128,128]^T) --------

__global__ __launch_bounds__(256)
void k_cvtw(const float* gw0, const float* gw1, const float* gw2,
            const float* wk, const float* wv, const float* wq, const float* ow,
            unsigned short* gwT0, unsigned short* gwT1, unsigned short* gwT2,
            unsigned short* wkvT, unsigned short* wqT, unsigned short* owT) {
  const float* src; unsigned short* dst;
  switch (blockIdx.y) {
    case 0: src = gw0; dst = gwT0; break;
    case 1: src = gw1; dst = gwT1; break;
    case 2: src = gw2; dst = gwT2; break;
    case 3: src = wk;  dst = wkvT; break;
    case 4: src = wv;  dst = wkvT + 128 * 128; break;
    case 5: src = wq;  dst = wqT; break;
    default: src = ow; dst = owT; break;
  }
  int t = blockIdx.x * 256 + threadIdx.x;   // grid.x = 64
  int r = t >> 7, c = t & 127;
  dst[(long)c * 128 + r] = f2b(src[t]);
}

// ---------------- register-only MFMA GEMM: C[M,NC] = A[M,128] @ BT^T ----------------
// BT is bf16 [NC,128] (pre-transposed). Block 256 thr = 4 waves -> 64 rows x 128 cols.
// A fragment: lane holds A[row=l&15][k=(l>>4)*8..+8]; B: BT[col=l&15][same k].

template<int OUTF32, int AF32>
__global__ __launch_bounds__(256)
void k_gemm_mfma(const void* __restrict__ A, const unsigned short* __restrict__ BT,
                 void* __restrict__ C, const float* __restrict__ bias, int M, int NC) {
  int tid = threadIdx.x;
  int lane = tid & 63;
  int w = tid >> 6;
  int lo = lane & 15, hi = lane >> 4;
  long rbase = (long)blockIdx.x * 64 + (w & 1) * 32;
  int cbase = blockIdx.y * 128 + (w >> 1) * 64;

  long r0 = rbase + lo, r1 = rbase + 16 + lo;
  long rr0 = r0 < M ? r0 : M - 1;
  long rr1 = r1 < M ? r1 : M - 1;

  f32x4 acc[2][4] = {};
#pragma unroll
  for (int ks = 0; ks < 4; ++ks) {
    int k0 = ks * 32 + hi * 8;
    bf16x8 a0, a1;
    if (AF32) {
      const float* Af = (const float*)A;
      union { bf16x8 v; unsigned short u[8]; } t0, t1;
      float4 p = *(const float4*)&Af[rr0 * 128 + k0];
      float4 q = *(const float4*)&Af[rr0 * 128 + k0 + 4];
      t0.u[0] = f2b(p.x); t0.u[1] = f2b(p.y); t0.u[2] = f2b(p.z); t0.u[3] = f2b(p.w);
      t0.u[4] = f2b(q.x); t0.u[5] = f2b(q.y); t0.u[6] = f2b(q.z); t0.u[7] = f2b(q.w);
      p = *(const float4*)&Af[rr1 * 128 + k0];
      q = *(const float4*)&Af[rr1 * 128 + k0 + 4];
      t1.u[0] = f2b(p.x); t1.u[1] = f2b(p.y); t1.u[2] = f2b(p.z); t1.u[3] = f2b(p.w);
      t1.u[4] = f2b(q.x); t1.u[5] = f2b(q.y); t1.u[6] = f2b(q.z); t1.u[7] = f2b(q.w);
      a0 = t0.v; a1 = t1.v;
    } else {
      const unsigned short* Ab = (const unsigned short*)A;
      a0 = *(const bf16x8*)&Ab[rr0 * 128 + k0];
      a1 = *(const bf16x8*)&Ab[rr1 * 128 + k0];
    }
#pragma unroll
    for (int cb = 0; cb < 4; ++cb) {
      bf16x8 b = *(const bf16x8*)&BT[(long)(cbase + cb * 16 + lo) * 128 + k0];
      acc[0][cb] = __builtin_amdgcn_mfma_f32_16x16x32_bf16(a0, b, acc[0][cb], 0, 0, 0);
      acc[1][cb] = __builtin_amdgcn_mfma_f32_16x16x32_bf16(a1, b, acc[1][cb], 0, 0, 0);
    }
  }
  // C/D layout: col = lane&15, row = (lane>>4)*4 + j  (per 16x16 fragment)
#pragma unroll
  for (int ab = 0; ab < 2; ++ab) {
    long rowb = rbase + ab * 16 + hi * 4;
#pragma unroll
    for (int j = 0; j < 4; ++j) {
      long row = rowb + j;
      if (row >= M) continue;
#pragma unroll
      for (int cb = 0; cb < 4; ++cb) {
        int col = cbase + cb * 16 + lo;
        float v = acc[ab][cb][j];
        if (OUTF32) ((float*)C)[row * NC + col] = v + bias[col];
        else        ((unsigned short*)C)[row * NC + col] = f2b(v);
      }
    }
  }
}

// ---------------- GCN aggregate + bias + ReLU + LN + residual (bf16 features) ----------

template<int PREV_F32>
__global__ __launch_bounds__(128)
void k_aggregate(const unsigned short* __restrict__ hw, const int* __restrict__ off,
                 const int* __restrict__ csr_src, const float* __restrict__ csr_norm,
                 const float* __restrict__ dinv, const float* __restrict__ bias,
                 const float* __restrict__ ln_g, const float* __restrict__ ln_b,
                 const void* __restrict__ prev, unsigned short* __restrict__ outp) {
  int node = blockIdx.x;
  int tid = threadIdx.x;
  float dn = dinv[node];
  float acc = b2f(hw[(long)node * 128 + tid]) * dn * dn;   // self loop
  int s0 = off[node], s1 = off[node + 1];
  for (int i = s0; i < s1; ++i) {
    int s = csr_src[i];
    acc += b2f(hw[(long)s * 128 + tid]) * csr_norm[i];
  }
  acc += bias[tid];
  acc = fmaxf(acc, 0.f);
  float sum = acc, sq = acc * acc;
#pragma unroll
  for (int m = 32; m; m >>= 1) { sum += __shfl_xor(sum, m); sq += __shfl_xor(sq, m); }
  __shared__ float ws0[2], ws1[2];
  if ((tid & 63) == 0) { ws0[tid >> 6] = sum; ws1[tid >> 6] = sq; }
  __syncthreads();
  sum = ws0[0] + ws0[1];
  sq  = ws1[0] + ws1[1];
  float mu = sum * (1.f / 128.f);
  float var = sq * (1.f / 128.f) - mu * mu;
  float v = (acc - mu) * rsqrtf(var + 1e-5f) * ln_g[tid] + ln_b[tid];
  long idx = (long)node * 128 + tid;
  float pv = PREV_F32 ? ((const float*)prev)[idx] : b2f(((const unsigned short*)prev)[idx]);
  outp[idx] = f2b(pv + v);
}

// ---------------- attention math + LN (memory-bound; 1 wave = 1 node) ----------------
// kv layout: [3, N, 256] bf16 (K | V per row). q: [N,128] bf16. Out: z bf16 [N,128].

__global__ __launch_bounds__(256)
void k_attn(const unsigned short* __restrict__ kv, const unsigned short* __restrict__ qb,
            const float* __restrict__ ln_g, const float* __restrict__ ln_b,
            unsigned short* __restrict__ zb, int N) {
  int lane = threadIdx.x & 63;
  long node = (long)blockIdx.x * 4 + (threadIdx.x >> 6);
  if (node >= N) return;
  int c = lane * 2;
  float2 q = ldb2(qb + node * 128 + c);
  float s[3], vx[3], vy[3];
#pragma unroll
  for (int m = 0; m < 3; ++m) {
    const unsigned short* base = kv + ((long)m * N + node) * 256;
    float2 k = ldb2(base + c);
    float2 v = ldb2(base + 128 + c);
    float p = q.x * k.x + q.y * k.y;
    p += __shfl_xor(p, 1); p += __shfl_xor(p, 2); p += __shfl_xor(p, 4);
    s[m] = p * 0.25f;   // /sqrt(16)
    vx[m] = v.x; vy[m] = v.y;
  }
  float mx = fmaxf(s[0], fmaxf(s[1], s[2]));
  float e0 = __expf(s[0] - mx), e1 = __expf(s[1] - mx), e2 = __expf(s[2] - mx);
  float inv = 1.f / (e0 + e1 + e2);
  float cx = (e0 * vx[0] + e1 * vx[1] + e2 * vx[2]) * inv;
  float cy = (e0 * vy[0] + e1 * vy[1] + e2 * vy[2]) * inv;
  float sum = cx + cy, sq = cx * cx + cy * cy;
#pragma unroll
  for (int m = 1; m < 64; m <<= 1) { sum += __shfl_xor(sum, m); sq += __shfl_xor(sq, m); }
  float mu = sum * (1.f / 128.f);
  float var = sq * (1.f / 128.f) - mu * mu;
  float rs = rsqrtf(var + 1e-5f);
  float zx = (cx - mu) * rs * ln_g[c] + ln_b[c];
  float zy = (cy - mu) * rs * ln_g[c + 1] + ln_b[c + 1];
  unsigned pk = (unsigned)f2b(zx) | ((unsigned)f2b(zy) << 16);
  *(unsigned*)&zb[node * 128 + c] = pk;
}

// ---------------- gather rows (fp32 zout) ----------------

__global__ void k_gather(const float* __restrict__ zout, const int* __restrict__ ids,
                         float* __restrict__ outp, int rows) {
  int t = blockIdx.x * blockDim.x + threadIdx.x;  // one float4 per thread
  if (t >= rows * 32) return;
  int row = t >> 5, c4 = t & 31;
  long id = ids[row];
  ((float4*)outp)[(long)row * 32 + c4] = ((const float4*)zout)[id * 32 + c4];
}

// ---------------- host ----------------

extern "C" void kernel_launch(void* const* d_in, const int* in_sizes, int n_in,
                              void* d_out, int out_size, void* d_ws, size_t ws_size,
                              hipStream_t stream) {
  const float* x = (const float*)d_in[0];
  const int* ei = (const int*)d_in[1];
  const int* ids[4] = {(const int*)d_in[2], (const int*)d_in[3],
                       (const int*)d_in[4], (const int*)d_in[5]};
  const float* gw[3] = {(const float*)d_in[7], (const float*)d_in[9], (const float*)d_in[11]};
  const float* gb[3] = {(const float*)d_in[8], (const float*)d_in[10], (const float*)d_in[12]};
  const float* wq = (const float*)d_in[13];
  const float* wk = (const float*)d_in[14];
  const float* wv = (const float*)d_in[15];
  const float* ln_g = (const float*)d_in[16];
  const float* ln_b = (const float*)d_in[17];
  const float* out_w = (const float*)d_in[18];
  const float* out_b = (const float*)d_in[19];

  const int N = in_sizes[0] / 128;
  const int E = in_sizes[1] / 2;
  const int P = in_sizes[2];

  char* w = (char*)d_ws;
  size_t o = 0;
  auto take = [&](size_t bytes) -> void* {
    void* p = w + o;
    o = (o + bytes + 255) & ~(size_t)255;
    return p;
  };
  int*   degi    = (int*)take((size_t)N * 4);
  int*   off     = (int*)take((size_t)(N + 1) * 4);
  int*   cursor  = (int*)take((size_t)N * 4);
  int*   part    = (int*)take(1024 * 4);
  float* dinv    = (float*)take((size_t)N * 4);
  int*   csr_src = (int*)take((size_t)E * 4);
  float* csr_nrm = (float*)take((size_t)E * 4);
  unsigned short* gwT0 = (unsigned short*)take(128 * 128 * 2);
  unsigned short* gwT1 = (unsigned short*)take(128 * 128 * 2);
  unsigned short* gwT2 = (unsigned short*)take(128 * 128 * 2);
  unsigned short* wkvT = (unsigned short*)take(256 * 128 * 2);
  unsigned short* wqT  = (unsigned short*)take(128 * 128 * 2);
  unsigned short* owT  = (unsigned short*)take(128 * 128 * 2);
  unsigned short* hw   = (unsigned short*)take((size_t)N * 128 * 2);      // also reused as z
  unsigned short* emball = (unsigned short*)take((size_t)3 * N * 128 * 2);
  unsigned short* kvb  = (unsigned short*)take((size_t)3 * N * 256 * 2);  // reused as zout f32
  unsigned short* qb   = (unsigned short*)take((size_t)N * 128 * 2);
  (void)ws_size; (void)n_in; (void)out_size;

  hipMemsetAsync(degi, 0, (size_t)N * 4, stream);
  hipMemsetAsync(cursor, 0, (size_t)N * 4, stream);

  int eb = (E + 255) / 256;
  int nb = (N + 255) / 256;
  k_degree<<<eb, 256, 0, stream>>>(ei + E, degi, E);
  k_dinv<<<nb, 256, 0, stream>>>(degi, dinv, N);
  k_part<<<nb, 256, 0, stream>>>(degi, part, N);
  k_scanpart<<<1, 1024, 0, stream>>>(part, nb, off + N);
  k_off<<<nb, 256, 0, stream>>>(degi, part, off, N);
  k_scatter<<<eb, 256, 0, stream>>>(ei, ei + E, dinv, off, cursor, csr_src, csr_nrm, E);
  k_cvtw<<<dim3(64, 7), 256, 0, stream>>>(gw[0], gw[1], gw[2], wk, wv, wq, out_w,
                                          gwT0, gwT1, gwT2, wkvT, wqT, owT);

  unsigned short* gwT[3] = {gwT0, gwT1, gwT2};
  int gx = (N + 63) / 64;
  // layer 0: A = x (fp32), prev = x (fp32)
  k_gemm_mfma<0, 1><<<dim3(gx, 1), 256, 0, stream>>>(x, gwT[0], hw, nullptr, N, 128);
  k_aggregate<1><<<N, 128, 0, stream>>>(hw, off, csr_src, csr_nrm, dinv, gb[0],
                                        ln_g, ln_b, x, emball);
  // layers 1,2
  for (int l = 1; l < 3; ++l) {
    unsigned short* prev = emball + (size_t)(l - 1) * N * 128;
    unsigned short* outp = emball + (size_t)l * N * 128;
    k_gemm_mfma<0, 0><<<dim3(gx, 1), 256, 0, stream>>>(prev, gwT[l], hw, nullptr, N, 128);
    k_aggregate<0><<<N, 128, 0, stream>>>(hw, off, csr_src, csr_nrm, dinv, gb[l],
                                          ln_g, ln_b, prev, outp);
  }

  // K|V for all 3 layers in one GEMM: [3N,128] @ [128,256]
  int gx3 = (3 * N + 63) / 64;
  k_gemm_mfma<0, 0><<<dim3(gx3, 2), 256, 0, stream>>>(emball, wkvT, kvb, nullptr, 3 * N, 256);
  // Q from layer-2 emb only
  k_gemm_mfma<0, 0><<<dim3(gx, 1), 256, 0, stream>>>(emball + (size_t)2 * N * 128, wqT,
                                                     qb, nullptr, N, 128);
  // attention + LN -> z (bf16, reuse hw)
  unsigned short* zb = hw;
  k_attn<<<(N + 3) / 4, 256, 0, stream>>>(kvb, qb, ln_g, ln_b, zb, N);
  // out projection -> fp32 zout (reuse kv buffer)
  float* zout = (float*)kvb;
  k_gemm_mfma<1, 0><<<dim3(gx, 1), 256, 0, stream>>>(zb, owT, zout, out_b, N, 128);

  float* outf = (float*)d_out;
  int gb2 = (P * 32 + 255) / 256;
  for (int s = 0; s < 4; ++s)
    k_gather<<<gb2, 256, 0, stream>>>(zout, ids[s], outf + (size_t)s * P * 128, P);
}

// Round 3
// 368.012 us; speedup vs baseline: 2.2366x; 1.3544x over previous
//
#include <hip/hip_runtime.h>
#include <math.h>

using bf16x8 = __attribute__((ext_vector_type(8))) short;
using f32x4  = __attribute__((ext_vector_type(4))) float;

__device__ __forceinline__ unsigned short f2b(float f) {
  unsigned u = __float_as_uint(f);
  u += 0x7FFFu + ((u >> 16) & 1u);
  return (unsigned short)(u >> 16);
}
__device__ __forceinline__ float b2f(unsigned short h) {
  return __uint_as_float((unsigned)h << 16);
}
__device__ __forceinline__ float2 upk(unsigned u) {
  return make_float2(__uint_as_float(u << 16), __uint_as_float(u & 0xFFFF0000u));
}
__device__ __forceinline__ float2 ldb2(const unsigned short* p) {
  return upk(*(const unsigned*)p);
}

// ---------------- graph prep ----------------

__global__ void k_degree(const int* __restrict__ dst, int* __restrict__ degi, int E) {
  int e = blockIdx.x * blockDim.x + threadIdx.x;
  if (e < E) atomicAdd(&degi[dst[e]], 1);
}

__global__ void k_dinv(const int* __restrict__ degi, float* __restrict__ dinv, int n) {
  int i = blockIdx.x * blockDim.x + threadIdx.x;
  if (i < n) dinv[i] = rsqrtf((float)(degi[i] + 1));  // +1 self-loop
}

// 3-phase exclusive scan of deg -> off
__global__ __launch_bounds__(256)
void k_part(const int* __restrict__ deg, int* __restrict__ part, int n) {
  __shared__ int l[256];
  int tid = threadIdx.x, i = blockIdx.x * 256 + tid;
  l[tid] = (i < n) ? deg[i] : 0;
  __syncthreads();
  for (int s = 128; s; s >>= 1) { if (tid < s) l[tid] += l[tid + s]; __syncthreads(); }
  if (!tid) part[blockIdx.x] = l[0];
}

__global__ __launch_bounds__(1024)
void k_scanpart(int* __restrict__ part, int np, int* __restrict__ off_n) {
  __shared__ int l[1024];
  int tid = threadIdx.x;
  int v = (tid < np) ? part[tid] : 0;
  l[tid] = v;
  __syncthreads();
  for (int s = 1; s < 1024; s <<= 1) {
    int t = (tid >= s) ? l[tid - s] : 0;
    __syncthreads();
    l[tid] += t;
    __syncthreads();
  }
  if (tid < np) part[tid] = l[tid] - v;   // exclusive
  if (tid == np - 1) *off_n = l[tid];     // total = E
}

__global__ __launch_bounds__(256)
void k_off(const int* __restrict__ deg, const int* __restrict__ part,
           int* __restrict__ off, int n) {
  __shared__ int l[256];
  int tid = threadIdx.x, i = blockIdx.x * 256 + tid;
  int v = (i < n) ? deg[i] : 0;
  l[tid] = v;
  __syncthreads();
  for (int s = 1; s < 256; s <<= 1) {
    int t = (tid >= s) ? l[tid - s] : 0;
    __syncthreads();
    l[tid] += t;
    __syncthreads();
  }
  if (i < n) off[i] = part[blockIdx.x] + l[tid] - v;
}

__global__ void k_scatter(const int* __restrict__ srcv, const int* __restrict__ dstv,
                          const float* __restrict__ dinv, const int* __restrict__ off,
                          int* __restrict__ cursor, int* __restrict__ csr_src,
                          float* __restrict__ csr_norm, int E) {
  int e = blockIdx.x * blockDim.x + threadIdx.x;
  if (e >= E) return;
  int d = dstv[e];
  int p = atomicAdd(&cursor[d], 1);
  int slot = off[d] + p;
  int s = srcv[e];
  csr_src[slot] = s;
  csr_norm[slot] = dinv[s] * dinv[d];
}

// ---------------- weight convert + transpose (fp32 [128,128] -> bf16 [128,128]^T) --------

__global__ __launch_bounds__(256)
void k_cvtw(const float* gw0, const float* gw1, const float* gw2,
            const float* wk, const float* wv, const float* wq, const float* ow,
            unsigned short* gwT0, unsigned short* gwT1, unsigned short* gwT2,
            unsigned short* wkvT, unsigned short* wqT, unsigned short* owT) {
  const float* src; unsigned short* dst;
  switch (blockIdx.y) {
    case 0: src = gw0; dst = gwT0; break;
    case 1: src = gw1; dst = gwT1; break;
    case 2: src = gw2; dst = gwT2; break;
    case 3: src = wk;  dst = wkvT; break;
    case 4: src = wv;  dst = wkvT + 128 * 128; break;
    case 5: src = wq;  dst = wqT; break;
    default: src = ow; dst = owT; break;
  }
  int t = blockIdx.x * 256 + threadIdx.x;   // grid.x = 64
  int r = t >> 7, c = t & 127;
  dst[(long)c * 128 + r] = f2b(src[t]);
}

// ---------------- register-only MFMA GEMM: C[M,NC] = A[M,128] @ BT^T ----------------

template<int OUTF32, int AF32>
__global__ __launch_bounds__(256)
void k_gemm_mfma(const void* __restrict__ A, const unsigned short* __restrict__ BT,
                 void* __restrict__ C, const float* __restrict__ bias, int M, int NC) {
  int tid = threadIdx.x;
  int lane = tid & 63;
  int w = tid >> 6;
  int lo = lane & 15, hi = lane >> 4;
  long rbase = (long)blockIdx.x * 64 + (w & 1) * 32;
  int cbase = blockIdx.y * 128 + (w >> 1) * 64;

  long r0 = rbase + lo, r1 = rbase + 16 + lo;
  long rr0 = r0 < M ? r0 : M - 1;
  long rr1 = r1 < M ? r1 : M - 1;

  f32x4 acc[2][4] = {};
#pragma unroll
  for (int ks = 0; ks < 4; ++ks) {
    int k0 = ks * 32 + hi * 8;
    bf16x8 a0, a1;
    if (AF32) {
      const float* Af = (const float*)A;
      union { bf16x8 v; unsigned short u[8]; } t0, t1;
      float4 p = *(const float4*)&Af[rr0 * 128 + k0];
      float4 q = *(const float4*)&Af[rr0 * 128 + k0 + 4];
      t0.u[0] = f2b(p.x); t0.u[1] = f2b(p.y); t0.u[2] = f2b(p.z); t0.u[3] = f2b(p.w);
      t0.u[4] = f2b(q.x); t0.u[5] = f2b(q.y); t0.u[6] = f2b(q.z); t0.u[7] = f2b(q.w);
      p = *(const float4*)&Af[rr1 * 128 + k0];
      q = *(const float4*)&Af[rr1 * 128 + k0 + 4];
      t1.u[0] = f2b(p.x); t1.u[1] = f2b(p.y); t1.u[2] = f2b(p.z); t1.u[3] = f2b(p.w);
      t1.u[4] = f2b(q.x); t1.u[5] = f2b(q.y); t1.u[6] = f2b(q.z); t1.u[7] = f2b(q.w);
      a0 = t0.v; a1 = t1.v;
    } else {
      const unsigned short* Ab = (const unsigned short*)A;
      a0 = *(const bf16x8*)&Ab[rr0 * 128 + k0];
      a1 = *(const bf16x8*)&Ab[rr1 * 128 + k0];
    }
#pragma unroll
    for (int cb = 0; cb < 4; ++cb) {
      bf16x8 b = *(const bf16x8*)&BT[(long)(cbase + cb * 16 + lo) * 128 + k0];
      acc[0][cb] = __builtin_amdgcn_mfma_f32_16x16x32_bf16(a0, b, acc[0][cb], 0, 0, 0);
      acc[1][cb] = __builtin_amdgcn_mfma_f32_16x16x32_bf16(a1, b, acc[1][cb], 0, 0, 0);
    }
  }
  // C/D layout: col = lane&15, row = (lane>>4)*4 + j
#pragma unroll
  for (int ab = 0; ab < 2; ++ab) {
    long rowb = rbase + ab * 16 + hi * 4;
#pragma unroll
    for (int j = 0; j < 4; ++j) {
      long row = rowb + j;
      if (row >= M) continue;
#pragma unroll
      for (int cb = 0; cb < 4; ++cb) {
        int col = cbase + cb * 16 + lo;
        float v = acc[ab][cb][j];
        if (OUTF32) ((float*)C)[row * NC + col] = v + bias[col];
        else        ((unsigned short*)C)[row * NC + col] = f2b(v);
      }
    }
  }
}

// ---------------- GCN aggregate + bias + ReLU + LN + residual ----------------
// One WAVE per node; lane handles 2 channels (u32 = 2 x bf16).
// Edge loop in fixed batches of 16 with predication: 16 independent row
// gathers in flight per lane -> breaks the serial dependent-load chain.

template<int PREV_F32>
__global__ __launch_bounds__(256)
void k_aggregate(const unsigned short* __restrict__ hw, const int* __restrict__ off,
                 const int* __restrict__ csr_src, const float* __restrict__ csr_norm,
                 const float* __restrict__ dinv, const float* __restrict__ bias,
                 const float* __restrict__ ln_g, const float* __restrict__ ln_b,
                 const void* __restrict__ prev, unsigned short* __restrict__ outp,
                 int N) {
  int lane = threadIdx.x & 63;
  int node = blockIdx.x * 4 + (threadIdx.x >> 6);
  if (node >= N) return;
  int c = lane * 2;
  float dn = dinv[node];
  float2 acc = upk(*(const unsigned*)&hw[(long)node * 128 + c]);
  acc.x *= dn * dn; acc.y *= dn * dn;       // self loop
  int s0 = off[node], s1 = off[node + 1];
  for (int i = s0; i < s1; i += 16) {
    int idx[16]; float nrm[16];
#pragma unroll
    for (int u = 0; u < 16; ++u) {
      int j = (i + u < s1) ? i + u : s1 - 1;
      idx[u] = csr_src[j];
      nrm[u] = (i + u < s1) ? csr_norm[j] : 0.f;
    }
    unsigned rv[16];
#pragma unroll
    for (int u = 0; u < 16; ++u)
      rv[u] = *(const unsigned*)&hw[(long)idx[u] * 128 + c];
#pragma unroll
    for (int u = 0; u < 16; ++u) {
      float2 f = upk(rv[u]);
      acc.x += f.x * nrm[u];
      acc.y += f.y * nrm[u];
    }
  }
  acc.x = fmaxf(acc.x + bias[c], 0.f);
  acc.y = fmaxf(acc.y + bias[c + 1], 0.f);
  // LayerNorm across the wave (128 channels)
  float sum = acc.x + acc.y, sq = acc.x * acc.x + acc.y * acc.y;
#pragma unroll
  for (int m = 1; m < 64; m <<= 1) { sum += __shfl_xor(sum, m); sq += __shfl_xor(sq, m); }
  float mu = sum * (1.f / 128.f);
  float var = sq * (1.f / 128.f) - mu * mu;
  float rs = rsqrtf(var + 1e-5f);
  float vx = (acc.x - mu) * rs * ln_g[c] + ln_b[c];
  float vy = (acc.y - mu) * rs * ln_g[c + 1] + ln_b[c + 1];
  long idxo = (long)node * 128 + c;
  float px, py;
  if (PREV_F32) {
    const float* pf = (const float*)prev;
    px = pf[idxo]; py = pf[idxo + 1];
  } else {
    float2 pv = ldb2((const unsigned short*)prev + idxo);
    px = pv.x; py = pv.y;
  }
  unsigned pk = (unsigned)f2b(px + vx) | ((unsigned)f2b(py + vy) << 16);
  *(unsigned*)&outp[idxo] = pk;
}

// ---------------- attention math + LN (memory-bound; 1 wave = 1 node) ----------------

__global__ __launch_bounds__(256)
void k_attn(const unsigned short* __restrict__ kv, const unsigned short* __restrict__ qb,
            const float* __restrict__ ln_g, const float* __restrict__ ln_b,
            unsigned short* __restrict__ zb, int N) {
  int lane = threadIdx.x & 63;
  long node = (long)blockIdx.x * 4 + (threadIdx.x >> 6);
  if (node >= N) return;
  int c = lane * 2;
  float2 q = ldb2(qb + node * 128 + c);
  float s[3], vx[3], vy[3];
#pragma unroll
  for (int m = 0; m < 3; ++m) {
    const unsigned short* base = kv + ((long)m * N + node) * 256;
    float2 k = ldb2(base + c);
    float2 v = ldb2(base + 128 + c);
    float p = q.x * k.x + q.y * k.y;
    p += __shfl_xor(p, 1); p += __shfl_xor(p, 2); p += __shfl_xor(p, 4);
    s[m] = p * 0.25f;   // /sqrt(16)
    vx[m] = v.x; vy[m] = v.y;
  }
  float mx = fmaxf(s[0], fmaxf(s[1], s[2]));
  float e0 = __expf(s[0] - mx), e1 = __expf(s[1] - mx), e2 = __expf(s[2] - mx);
  float inv = 1.f / (e0 + e1 + e2);
  float cx = (e0 * vx[0] + e1 * vx[1] + e2 * vx[2]) * inv;
  float cy = (e0 * vy[0] + e1 * vy[1] + e2 * vy[2]) * inv;
  float sum = cx + cy, sq = cx * cx + cy * cy;
#pragma unroll
  for (int m = 1; m < 64; m <<= 1) { sum += __shfl_xor(sum, m); sq += __shfl_xor(sq, m); }
  float mu = sum * (1.f / 128.f);
  float var = sq * (1.f / 128.f) - mu * mu;
  float rs = rsqrtf(var + 1e-5f);
  float zx = (cx - mu) * rs * ln_g[c] + ln_b[c];
  float zy = (cy - mu) * rs * ln_g[c + 1] + ln_b[c + 1];
  unsigned pk = (unsigned)f2b(zx) | ((unsigned)f2b(zy) << 16);
  *(unsigned*)&zb[node * 128 + c] = pk;
}

// ---------------- gather rows (fp32 zout); blockIdx.y = id set ----------------

__global__ void k_gather4(const float* __restrict__ zout,
                          const int* __restrict__ ids0, const int* __restrict__ ids1,
                          const int* __restrict__ ids2, const int* __restrict__ ids3,
                          float* __restrict__ outp, int rows) {
  int t = blockIdx.x * blockDim.x + threadIdx.x;  // one float4 per thread
  if (t >= rows * 32) return;
  int s = blockIdx.y;
  const int* ids = (s == 0) ? ids0 : (s == 1) ? ids1 : (s == 2) ? ids2 : ids3;
  int row = t >> 5, c4 = t & 31;
  long id = ids[row];
  ((float4*)outp)[((long)s * rows + row) * 32 + c4] = ((const float4*)zout)[id * 32 + c4];
}

// ---------------- host ----------------

extern "C" void kernel_launch(void* const* d_in, const int* in_sizes, int n_in,
                              void* d_out, int out_size, void* d_ws, size_t ws_size,
                              hipStream_t stream) {
  const float* x = (const float*)d_in[0];
  const int* ei = (const int*)d_in[1];
  const int* ids[4] = {(const int*)d_in[2], (const int*)d_in[3],
                       (const int*)d_in[4], (const int*)d_in[5]};
  const float* gw[3] = {(const float*)d_in[7], (const float*)d_in[9], (const float*)d_in[11]};
  const float* gb[3] = {(const float*)d_in[8], (const float*)d_in[10], (const float*)d_in[12]};
  const float* wq = (const float*)d_in[13];
  const float* wk = (const float*)d_in[14];
  const float* wv = (const float*)d_in[15];
  const float* ln_g = (const float*)d_in[16];
  const float* ln_b = (const float*)d_in[17];
  const float* out_w = (const float*)d_in[18];
  const float* out_b = (const float*)d_in[19];

  const int N = in_sizes[0] / 128;
  const int E = in_sizes[1] / 2;
  const int P = in_sizes[2];

  char* w = (char*)d_ws;
  size_t o = 0;
  auto take = [&](size_t bytes) -> void* {
    void* p = w + o;
    o = (o + bytes + 255) & ~(size_t)255;
    return p;
  };
  int*   degi    = (int*)take((size_t)N * 4);
  int*   off     = (int*)take((size_t)(N + 1) * 4);
  int*   cursor  = (int*)take((size_t)N * 4);
  int*   part    = (int*)take(1024 * 4);
  float* dinv    = (float*)take((size_t)N * 4);
  int*   csr_src = (int*)take((size_t)E * 4);
  float* csr_nrm = (float*)take((size_t)E * 4);
  unsigned short* gwT0 = (unsigned short*)take(128 * 128 * 2);
  unsigned short* gwT1 = (unsigned short*)take(128 * 128 * 2);
  unsigned short* gwT2 = (unsigned short*)take(128 * 128 * 2);
  unsigned short* wkvT = (unsigned short*)take(256 * 128 * 2);
  unsigned short* wqT  = (unsigned short*)take(128 * 128 * 2);
  unsigned short* owT  = (unsigned short*)take(128 * 128 * 2);
  unsigned short* hw   = (unsigned short*)take((size_t)N * 128 * 2);      // also reused as z
  unsigned short* emball = (unsigned short*)take((size_t)3 * N * 128 * 2);
  unsigned short* kvb  = (unsigned short*)take((size_t)3 * N * 256 * 2);  // reused as zout f32
  unsigned short* qb   = (unsigned short*)take((size_t)N * 128 * 2);
  (void)ws_size; (void)n_in; (void)out_size;

  hipMemsetAsync(degi, 0, (size_t)N * 4, stream);
  hipMemsetAsync(cursor, 0, (size_t)N * 4, stream);

  int eb = (E + 255) / 256;
  int nb = (N + 255) / 256;
  k_degree<<<eb, 256, 0, stream>>>(ei + E, degi, E);
  k_dinv<<<nb, 256, 0, stream>>>(degi, dinv, N);
  k_part<<<nb, 256, 0, stream>>>(degi, part, N);
  k_scanpart<<<1, 1024, 0, stream>>>(part, nb, off + N);
  k_off<<<nb, 256, 0, stream>>>(degi, part, off, N);
  k_scatter<<<eb, 256, 0, stream>>>(ei, ei + E, dinv, off, cursor, csr_src, csr_nrm, E);
  k_cvtw<<<dim3(64, 7), 256, 0, stream>>>(gw[0], gw[1], gw[2], wk, wv, wq, out_w,
                                          gwT0, gwT1, gwT2, wkvT, wqT, owT);

  unsigned short* gwT[3] = {gwT0, gwT1, gwT2};
  int gx = (N + 63) / 64;
  int ab = (N + 3) / 4;
  // layer 0: A = x (fp32), prev = x (fp32)
  k_gemm_mfma<0, 1><<<dim3(gx, 1), 256, 0, stream>>>(x, gwT[0], hw, nullptr, N, 128);
  k_aggregate<1><<<ab, 256, 0, stream>>>(hw, off, csr_src, csr_nrm, dinv, gb[0],
                                         ln_g, ln_b, x, emball, N);
  // layers 1,2
  for (int l = 1; l < 3; ++l) {
    unsigned short* prev = emball + (size_t)(l - 1) * N * 128;
    unsigned short* outp = emball + (size_t)l * N * 128;
    k_gemm_mfma<0, 0><<<dim3(gx, 1), 256, 0, stream>>>(prev, gwT[l], hw, nullptr, N, 128);
    k_aggregate<0><<<ab, 256, 0, stream>>>(hw, off, csr_src, csr_nrm, dinv, gb[l],
                                           ln_g, ln_b, prev, outp, N);
  }

  // K|V for all 3 layers in one GEMM: [3N,128] @ [128,256]
  int gx3 = (3 * N + 63) / 64;
  k_gemm_mfma<0, 0><<<dim3(gx3, 2), 256, 0, stream>>>(emball, wkvT, kvb, nullptr, 3 * N, 256);
  // Q from layer-2 emb only
  k_gemm_mfma<0, 0><<<dim3(gx, 1), 256, 0, stream>>>(emball + (size_t)2 * N * 128, wqT,
                                                     qb, nullptr, N, 128);
  // attention + LN -> z (bf16, reuse hw)
  unsigned short* zb = hw;
  k_attn<<<ab, 256, 0, stream>>>(kvb, qb, ln_g, ln_b, zb, N);
  // out projection -> fp32 zout (reuse kv buffer)
  float* zout = (float*)kvb;
  k_gemm_mfma<1, 0><<<dim3(gx, 1), 256, 0, stream>>>(zb, owT, zout, out_b, N, 128);

  float* outf = (float*)d_out;
  int gb2 = (P * 32 + 255) / 256;
  k_gather4<<<dim3(gb2, 4), 256, 0, stream>>>(zout, ids[0], ids[1], ids[2], ids[3],
                                              outf, P);
}

// Round 4
// 337.855 us; speedup vs baseline: 2.4362x; 1.0893x over previous
//
#include <hip/hip_runtime.h>
#include <math.h>

using bf16x8 = __attribute__((ext_vector_type(8))) short;
using f32x4  = __attribute__((ext_vector_type(4))) float;

__device__ __forceinline__ unsigned short f2b(float f) {
  unsigned u = __float_as_uint(f);
  u += 0x7FFFu + ((u >> 16) & 1u);
  return (unsigned short)(u >> 16);
}
__device__ __forceinline__ float b2f(unsigned short h) {
  return __uint_as_float((unsigned)h << 16);
}
__device__ __forceinline__ float2 upk(unsigned u) {
  return make_float2(__uint_as_float(u << 16), __uint_as_float(u & 0xFFFF0000u));
}
__device__ __forceinline__ float2 ldb2(const unsigned short* p) {
  return upk(*(const unsigned*)p);
}

// ---------------- graph prep ----------------

__global__ void k_degree(const int* __restrict__ dst, int* __restrict__ degi, int E) {
  int e = blockIdx.x * blockDim.x + threadIdx.x;
  if (e < E) atomicAdd(&degi[dst[e]], 1);
}

__global__ void k_dinv(const int* __restrict__ degi, float* __restrict__ dinv, int n) {
  int i = blockIdx.x * blockDim.x + threadIdx.x;
  if (i < n) dinv[i] = rsqrtf((float)(degi[i] + 1));  // +1 self-loop
}

// 3-phase exclusive scan of deg -> off
__global__ __launch_bounds__(256)
void k_part(const int* __restrict__ deg, int* __restrict__ part, int n) {
  __shared__ int l[256];
  int tid = threadIdx.x, i = blockIdx.x * 256 + tid;
  l[tid] = (i < n) ? deg[i] : 0;
  __syncthreads();
  for (int s = 128; s; s >>= 1) { if (tid < s) l[tid] += l[tid + s]; __syncthreads(); }
  if (!tid) part[blockIdx.x] = l[0];
}

__global__ __launch_bounds__(1024)
void k_scanpart(int* __restrict__ part, int np, int* __restrict__ off_n) {
  __shared__ int l[1024];
  int tid = threadIdx.x;
  int v = (tid < np) ? part[tid] : 0;
  l[tid] = v;
  __syncthreads();
  for (int s = 1; s < 1024; s <<= 1) {
    int t = (tid >= s) ? l[tid - s] : 0;
    __syncthreads();
    l[tid] += t;
    __syncthreads();
  }
  if (tid < np) part[tid] = l[tid] - v;   // exclusive
  if (tid == np - 1) *off_n = l[tid];     // total = E
}

__global__ __launch_bounds__(256)
void k_off(const int* __restrict__ deg, const int* __restrict__ part,
           int* __restrict__ off, int n) {
  __shared__ int l[256];
  int tid = threadIdx.x, i = blockIdx.x * 256 + tid;
  int v = (i < n) ? deg[i] : 0;
  l[tid] = v;
  __syncthreads();
  for (int s = 1; s < 256; s <<= 1) {
    int t = (tid >= s) ? l[tid - s] : 0;
    __syncthreads();
    l[tid] += t;
    __syncthreads();
  }
  if (i < n) off[i] = part[blockIdx.x] + l[tid] - v;
}

__global__ void k_scatter(const int* __restrict__ srcv, const int* __restrict__ dstv,
                          const float* __restrict__ dinv, const int* __restrict__ off,
                          int* __restrict__ cursor, int* __restrict__ csr_src,
                          float* __restrict__ csr_norm, int E) {
  int e = blockIdx.x * blockDim.x + threadIdx.x;
  if (e >= E) return;
  int d = dstv[e];
  int p = atomicAdd(&cursor[d], 1);
  int slot = off[d] + p;
  int s = srcv[e];
  csr_src[slot] = s;
  csr_norm[slot] = dinv[s] * dinv[d];
}

// ---------------- weight convert + transpose (fp32 [128,128] -> bf16 [128,128]^T) --------

__global__ __launch_bounds__(256)
void k_cvtw(const float* gw0, const float* gw1, const float* gw2,
            const float* wk, const float* wv, const float* wq, const float* ow,
            unsigned short* gwT0, unsigned short* gwT1, unsigned short* gwT2,
            unsigned short* wkvT, unsigned short* wqT, unsigned short* owT) {
  const float* src; unsigned short* dst;
  switch (blockIdx.y) {
    case 0: src = gw0; dst = gwT0; break;
    case 1: src = gw1; dst = gwT1; break;
    case 2: src = gw2; dst = gwT2; break;
    case 3: src = wk;  dst = wkvT; break;
    case 4: src = wv;  dst = wkvT + 128 * 128; break;
    case 5: src = wq;  dst = wqT; break;
    default: src = ow; dst = owT; break;
  }
  int t = blockIdx.x * 256 + threadIdx.x;   // grid.x = 64
  int r = t >> 7, c = t & 127;
  dst[(long)c * 128 + r] = f2b(src[t]);
}

// ---------------- register-only MFMA GEMM: C[M,NC] = A[M,128] @ BT^T ----------------

template<int OUTF32, int AF32>
__global__ __launch_bounds__(256)
void k_gemm_mfma(const void* __restrict__ A, const unsigned short* __restrict__ BT,
                 void* __restrict__ C, const float* __restrict__ bias, int M, int NC) {
  int tid = threadIdx.x;
  int lane = tid & 63;
  int w = tid >> 6;
  int lo = lane & 15, hi = lane >> 4;
  long rbase = (long)blockIdx.x * 64 + (w & 1) * 32;
  int cbase = blockIdx.y * 128 + (w >> 1) * 64;

  long r0 = rbase + lo, r1 = rbase + 16 + lo;
  long rr0 = r0 < M ? r0 : M - 1;
  long rr1 = r1 < M ? r1 : M - 1;

  f32x4 acc[2][4] = {};
#pragma unroll
  for (int ks = 0; ks < 4; ++ks) {
    int k0 = ks * 32 + hi * 8;
    bf16x8 a0, a1;
    if (AF32) {
      const float* Af = (const float*)A;
      union { bf16x8 v; unsigned short u[8]; } t0, t1;
      float4 p = *(const float4*)&Af[rr0 * 128 + k0];
      float4 q = *(const float4*)&Af[rr0 * 128 + k0 + 4];
      t0.u[0] = f2b(p.x); t0.u[1] = f2b(p.y); t0.u[2] = f2b(p.z); t0.u[3] = f2b(p.w);
      t0.u[4] = f2b(q.x); t0.u[5] = f2b(q.y); t0.u[6] = f2b(q.z); t0.u[7] = f2b(q.w);
      p = *(const float4*)&Af[rr1 * 128 + k0];
      q = *(const float4*)&Af[rr1 * 128 + k0 + 4];
      t1.u[0] = f2b(p.x); t1.u[1] = f2b(p.y); t1.u[2] = f2b(p.z); t1.u[3] = f2b(p.w);
      t1.u[4] = f2b(q.x); t1.u[5] = f2b(q.y); t1.u[6] = f2b(q.z); t1.u[7] = f2b(q.w);
      a0 = t0.v; a1 = t1.v;
    } else {
      const unsigned short* Ab = (const unsigned short*)A;
      a0 = *(const bf16x8*)&Ab[rr0 * 128 + k0];
      a1 = *(const bf16x8*)&Ab[rr1 * 128 + k0];
    }
#pragma unroll
    for (int cb = 0; cb < 4; ++cb) {
      bf16x8 b = *(const bf16x8*)&BT[(long)(cbase + cb * 16 + lo) * 128 + k0];
      acc[0][cb] = __builtin_amdgcn_mfma_f32_16x16x32_bf16(a0, b, acc[0][cb], 0, 0, 0);
      acc[1][cb] = __builtin_amdgcn_mfma_f32_16x16x32_bf16(a1, b, acc[1][cb], 0, 0, 0);
    }
  }
  // C/D layout: col = lane&15, row = (lane>>4)*4 + j
#pragma unroll
  for (int ab = 0; ab < 2; ++ab) {
    long rowb = rbase + ab * 16 + hi * 4;
#pragma unroll
    for (int j = 0; j < 4; ++j) {
      long row = rowb + j;
      if (row >= M) continue;
#pragma unroll
      for (int cb = 0; cb < 4; ++cb) {
        int col = cbase + cb * 16 + lo;
        float v = acc[ab][cb][j];
        if (OUTF32) ((float*)C)[row * NC + col] = v + bias[col];
        else        ((unsigned short*)C)[row * NC + col] = f2b(v);
      }
    }
  }
}

// ---------------- GCN aggregate + bias + ReLU + LN + residual ----------------
// One WAVE per node; lane handles 2 channels. Edge loop in batches of 16 with
// predication: 16 independent row gathers in flight.

template<int PREV_F32>
__global__ __launch_bounds__(256)
void k_aggregate(const unsigned short* __restrict__ hw, const int* __restrict__ off,
                 const int* __restrict__ csr_src, const float* __restrict__ csr_norm,
                 const float* __restrict__ dinv, const float* __restrict__ bias,
                 const float* __restrict__ ln_g, const float* __restrict__ ln_b,
                 const void* __restrict__ prev, unsigned short* __restrict__ outp,
                 int N) {
  int lane = threadIdx.x & 63;
  int node = blockIdx.x * 4 + (threadIdx.x >> 6);
  if (node >= N) return;
  int c = lane * 2;
  float dn = dinv[node];
  float2 acc = upk(*(const unsigned*)&hw[(long)node * 128 + c]);
  acc.x *= dn * dn; acc.y *= dn * dn;       // self loop
  int s0 = off[node], s1 = off[node + 1];
  for (int i = s0; i < s1; i += 16) {
    int idx[16]; float nrm[16];
#pragma unroll
    for (int u = 0; u < 16; ++u) {
      int j = (i + u < s1) ? i + u : s1 - 1;
      idx[u] = csr_src[j];
      nrm[u] = (i + u < s1) ? csr_norm[j] : 0.f;
    }
    unsigned rv[16];
#pragma unroll
    for (int u = 0; u < 16; ++u)
      rv[u] = *(const unsigned*)&hw[(long)idx[u] * 128 + c];
#pragma unroll
    for (int u = 0; u < 16; ++u) {
      float2 f = upk(rv[u]);
      acc.x += f.x * nrm[u];
      acc.y += f.y * nrm[u];
    }
  }
  acc.x = fmaxf(acc.x + bias[c], 0.f);
  acc.y = fmaxf(acc.y + bias[c + 1], 0.f);
  float sum = acc.x + acc.y, sq = acc.x * acc.x + acc.y * acc.y;
#pragma unroll
  for (int m = 1; m < 64; m <<= 1) { sum += __shfl_xor(sum, m); sq += __shfl_xor(sq, m); }
  float mu = sum * (1.f / 128.f);
  float var = sq * (1.f / 128.f) - mu * mu;
  float rs = rsqrtf(var + 1e-5f);
  float vx = (acc.x - mu) * rs * ln_g[c] + ln_b[c];
  float vy = (acc.y - mu) * rs * ln_g[c + 1] + ln_b[c + 1];
  long idxo = (long)node * 128 + c;
  float px, py;
  if (PREV_F32) {
    const float* pf = (const float*)prev;
    px = pf[idxo]; py = pf[idxo + 1];
  } else {
    float2 pv = ldb2((const unsigned short*)prev + idxo);
    px = pv.x; py = pv.y;
  }
  unsigned pk = (unsigned)f2b(px + vx) | ((unsigned)f2b(py + vy) << 16);
  *(unsigned*)&outp[idxo] = pk;
}

// ---------------- fused: kv-proj + q-proj + attention + LN + out-proj ----------------
// Block = 256 thr (4 waves) handles 16 nodes. emb layout [3][N][128] bf16:
// phase-1 row-fragment l <-> layer l (rows l*N + n0 + lane). All intermediates
// stay in LDS; only emb is read and zout (f32) written to global.

__global__ __launch_bounds__(256)
void k_attn_fused(const unsigned short* __restrict__ emb,   // [3][N][128]
                  const unsigned short* __restrict__ wkvT,  // [256][128] (K cols | V cols)
                  const unsigned short* __restrict__ wqT,   // [128][128]
                  const unsigned short* __restrict__ owT,   // [128][128]
                  const float* __restrict__ ln_g, const float* __restrict__ ln_b,
                  const float* __restrict__ out_b,
                  float* __restrict__ zout, int N) {
  __shared__ unsigned short kvl[48 * 256];  // row = l*16+node : [K 0..127 | V 128..255]
  __shared__ unsigned short ql[16 * 128];
  __shared__ unsigned short zl[16 * 128];   // XOR-swizzled (byte ^= (row&7)<<4)

  int tid = threadIdx.x, lane = tid & 63, w = tid >> 6;
  int lo = lane & 15, hi = lane >> 4;
  long n0 = (long)blockIdx.x * 16;
  long nr = n0 + lo; if (nr >= N) nr = N - 1;

  // ---- phase 1: KV[48,256] = emb-tile @ wkvT^T ; this wave: cols w*64..+64
  {
    int cb0 = w * 64;
    f32x4 acc[3][4] = {};
#pragma unroll
    for (int ks = 0; ks < 4; ++ks) {
      int k0 = ks * 32 + hi * 8;
      bf16x8 a[3];
#pragma unroll
      for (int l = 0; l < 3; ++l)
        a[l] = *(const bf16x8*)&emb[((long)l * N + nr) * 128 + k0];
#pragma unroll
      for (int cf = 0; cf < 4; ++cf) {
        bf16x8 b = *(const bf16x8*)&wkvT[(long)(cb0 + cf * 16 + lo) * 128 + k0];
#pragma unroll
        for (int l = 0; l < 3; ++l)
          acc[l][cf] = __builtin_amdgcn_mfma_f32_16x16x32_bf16(a[l], b, acc[l][cf], 0, 0, 0);
      }
    }
#pragma unroll
    for (int l = 0; l < 3; ++l)
#pragma unroll
      for (int cf = 0; cf < 4; ++cf)
#pragma unroll
        for (int j = 0; j < 4; ++j)
          kvl[(l * 16 + hi * 4 + j) * 256 + cb0 + cf * 16 + lo] = f2b(acc[l][cf][j]);
  }

  // ---- phase 2: Q[16,128] = layer2-tile @ wqT^T ; this wave: cols w*32..+32
  {
    int cq0 = w * 32;
    f32x4 aq[2] = {};
#pragma unroll
    for (int ks = 0; ks < 4; ++ks) {
      int k0 = ks * 32 + hi * 8;
      bf16x8 a = *(const bf16x8*)&emb[(2L * N + nr) * 128 + k0];
#pragma unroll
      for (int cf = 0; cf < 2; ++cf) {
        bf16x8 b = *(const bf16x8*)&wqT[(long)(cq0 + cf * 16 + lo) * 128 + k0];
        aq[cf] = __builtin_amdgcn_mfma_f32_16x16x32_bf16(a, b, aq[cf], 0, 0, 0);
      }
    }
#pragma unroll
    for (int cf = 0; cf < 2; ++cf)
#pragma unroll
      for (int j = 0; j < 4; ++j)
        ql[(hi * 4 + j) * 128 + cq0 + cf * 16 + lo] = f2b(aq[cf][j]);
  }
  __syncthreads();

  // ---- phase 3: attention + LN ; wave handles nodes w*4 .. w*4+3
  {
    const unsigned* kvu = (const unsigned*)kvl;
    const unsigned* qu  = (const unsigned*)ql;
    int c = lane * 2;
    float gx = ln_g[c], gy = ln_g[c + 1], bx = ln_b[c], by = ln_b[c + 1];
#pragma unroll
    for (int it = 0; it < 4; ++it) {
      int node = w * 4 + it;
      float2 q = upk(qu[node * 64 + lane]);
      float s[3], vx[3], vy[3];
#pragma unroll
      for (int m = 0; m < 3; ++m) {
        int row = m * 16 + node;
        float2 k = upk(kvu[row * 128 + lane]);
        float2 v = upk(kvu[row * 128 + 64 + lane]);
        float p = q.x * k.x + q.y * k.y;
        p += __shfl_xor(p, 1); p += __shfl_xor(p, 2); p += __shfl_xor(p, 4);
        s[m] = p * 0.25f;   // /sqrt(16)
        vx[m] = v.x; vy[m] = v.y;
      }
      float mx = fmaxf(s[0], fmaxf(s[1], s[2]));
      float e0 = __expf(s[0] - mx), e1 = __expf(s[1] - mx), e2 = __expf(s[2] - mx);
      float inv = 1.f / (e0 + e1 + e2);
      float cx = (e0 * vx[0] + e1 * vx[1] + e2 * vx[2]) * inv;
      float cy = (e0 * vy[0] + e1 * vy[1] + e2 * vy[2]) * inv;
      float sum = cx + cy, sq = cx * cx + cy * cy;
#pragma unroll
      for (int m = 1; m < 64; m <<= 1) { sum += __shfl_xor(sum, m); sq += __shfl_xor(sq, m); }
      float mu = sum * (1.f / 128.f);
      float var = sq * (1.f / 128.f) - mu * mu;
      float rs = rsqrtf(var + 1e-5f);
      unsigned pk = (unsigned)f2b((cx - mu) * rs * gx + bx) |
                    ((unsigned)f2b((cy - mu) * rs * gy + by) << 16);
      *(unsigned*)((char*)zl + node * 256 + ((lane * 4) ^ ((node & 7) << 4))) = pk;
    }
  }
  __syncthreads();

  // ---- phase 4: zout[16,128] = z @ owT^T + out_b ; this wave: cols w*32..+32
  {
    int co0 = w * 32;
    f32x4 ao[2] = {};
#pragma unroll
    for (int ks = 0; ks < 4; ++ks) {
      int k0 = ks * 32 + hi * 8;
      bf16x8 a = *(const bf16x8*)((const char*)zl + lo * 256 + (((k0 * 2) ^ ((lo & 7) << 4))));
#pragma unroll
      for (int cf = 0; cf < 2; ++cf) {
        bf16x8 b = *(const bf16x8*)&owT[(long)(co0 + cf * 16 + lo) * 128 + k0];
        ao[cf] = __builtin_amdgcn_mfma_f32_16x16x32_bf16(a, b, ao[cf], 0, 0, 0);
      }
    }
#pragma unroll
    for (int cf = 0; cf < 2; ++cf)
#pragma unroll
      for (int j = 0; j < 4; ++j) {
        long gn = n0 + hi * 4 + j;
        int col = co0 + cf * 16 + lo;
        if (gn < N) zout[gn * 128 + col] = ao[cf][j] + out_b[col];
      }
  }
}

// ---------------- gather rows (fp32 zout); blockIdx.y = id set ----------------

__global__ void k_gather4(const float* __restrict__ zout,
                          const int* __restrict__ ids0, const int* __restrict__ ids1,
                          const int* __restrict__ ids2, const int* __restrict__ ids3,
                          float* __restrict__ outp, int rows) {
  int t = blockIdx.x * blockDim.x + threadIdx.x;  // one float4 per thread
  if (t >= rows * 32) return;
  int s = blockIdx.y;
  const int* ids = (s == 0) ? ids0 : (s == 1) ? ids1 : (s == 2) ? ids2 : ids3;
  int row = t >> 5, c4 = t & 31;
  long id = ids[row];
  ((float4*)outp)[((long)s * rows + row) * 32 + c4] = ((const float4*)zout)[id * 32 + c4];
}

// ---------------- host ----------------

extern "C" void kernel_launch(void* const* d_in, const int* in_sizes, int n_in,
                              void* d_out, int out_size, void* d_ws, size_t ws_size,
                              hipStream_t stream) {
  const float* x = (const float*)d_in[0];
  const int* ei = (const int*)d_in[1];
  const int* ids[4] = {(const int*)d_in[2], (const int*)d_in[3],
                       (const int*)d_in[4], (const int*)d_in[5]};
  const float* gw[3] = {(const float*)d_in[7], (const float*)d_in[9], (const float*)d_in[11]};
  const float* gb[3] = {(const float*)d_in[8], (const float*)d_in[10], (const float*)d_in[12]};
  const float* wq = (const float*)d_in[13];
  const float* wk = (const float*)d_in[14];
  const float* wv = (const float*)d_in[15];
  const float* ln_g = (const float*)d_in[16];
  const float* ln_b = (const float*)d_in[17];
  const float* out_w = (const float*)d_in[18];
  const float* out_b = (const float*)d_in[19];

  const int N = in_sizes[0] / 128;
  const int E = in_sizes[1] / 2;
  const int P = in_sizes[2];

  char* w = (char*)d_ws;
  size_t o = 0;
  auto take = [&](size_t bytes) -> void* {
    void* p = w + o;
    o = (o + bytes + 255) & ~(size_t)255;
    return p;
  };
  int*   degi    = (int*)take((size_t)N * 4);
  int*   off     = (int*)take((size_t)(N + 1) * 4);
  int*   cursor  = (int*)take((size_t)N * 4);
  int*   part    = (int*)take(1024 * 4);
  float* dinv    = (float*)take((size_t)N * 4);
  int*   csr_src = (int*)take((size_t)E * 4);
  float* csr_nrm = (float*)take((size_t)E * 4);
  unsigned short* gwT0 = (unsigned short*)take(128 * 128 * 2);
  unsigned short* gwT1 = (unsigned short*)take(128 * 128 * 2);
  unsigned short* gwT2 = (unsigned short*)take(128 * 128 * 2);
  unsigned short* wkvT = (unsigned short*)take(256 * 128 * 2);
  unsigned short* wqT  = (unsigned short*)take(128 * 128 * 2);
  unsigned short* owT  = (unsigned short*)take(128 * 128 * 2);
  unsigned short* hw   = (unsigned short*)take((size_t)N * 128 * 2);
  unsigned short* emball = (unsigned short*)take((size_t)3 * N * 128 * 2);
  float* zout = (float*)take((size_t)N * 128 * 4);
  (void)ws_size; (void)n_in; (void)out_size;

  hipMemsetAsync(degi, 0, (size_t)N * 4, stream);
  hipMemsetAsync(cursor, 0, (size_t)N * 4, stream);

  int eb = (E + 255) / 256;
  int nb = (N + 255) / 256;
  k_degree<<<eb, 256, 0, stream>>>(ei + E, degi, E);
  k_dinv<<<nb, 256, 0, stream>>>(degi, dinv, N);
  k_part<<<nb, 256, 0, stream>>>(degi, part, N);
  k_scanpart<<<1, 1024, 0, stream>>>(part, nb, off + N);
  k_off<<<nb, 256, 0, stream>>>(degi, part, off, N);
  k_scatter<<<eb, 256, 0, stream>>>(ei, ei + E, dinv, off, cursor, csr_src, csr_nrm, E);
  k_cvtw<<<dim3(64, 7), 256, 0, stream>>>(gw[0], gw[1], gw[2], wk, wv, wq, out_w,
                                          gwT0, gwT1, gwT2, wkvT, wqT, owT);

  unsigned short* gwT[3] = {gwT0, gwT1, gwT2};
  int gx = (N + 63) / 64;
  int ab = (N + 3) / 4;
  // layer 0: A = x (fp32), prev = x (fp32)
  k_gemm_mfma<0, 1><<<dim3(gx, 1), 256, 0, stream>>>(x, gwT[0], hw, nullptr, N, 128);
  k_aggregate<1><<<ab, 256, 0, stream>>>(hw, off, csr_src, csr_nrm, dinv, gb[0],
                                         ln_g, ln_b, x, emball, N);
  // layers 1,2
  for (int l = 1; l < 3; ++l) {
    unsigned short* prev = emball + (size_t)(l - 1) * N * 128;
    unsigned short* outp = emball + (size_t)l * N * 128;
    k_gemm_mfma<0, 0><<<dim3(gx, 1), 256, 0, stream>>>(prev, gwT[l], hw, nullptr, N, 128);
    k_aggregate<0><<<ab, 256, 0, stream>>>(hw, off, csr_src, csr_nrm, dinv, gb[l],
                                           ln_g, ln_b, prev, outp, N);
  }

  // fused kv/q projections + attention + LN + out-proj
  k_attn_fused<<<(N + 15) / 16, 256, 0, stream>>>(emball, wkvT, wqT, owT,
                                                  ln_g, ln_b, out_b, zout, N);

  float* outf = (float*)d_out;
  int gb2 = (P * 32 + 255) / 256;
  k_gather4<<<dim3(gb2, 4), 256, 0, stream>>>(zout, ids[0], ids[1], ids[2], ids[3],
                                              outf, P);
}

// Round 5
// 308.622 us; speedup vs baseline: 2.6670x; 1.0947x over previous
//
#include <hip/hip_runtime.h>
#include <math.h>

using bf16x8 = __attribute__((ext_vector_type(8))) short;
using f32x4  = __attribute__((ext_vector_type(4))) float;

__device__ __forceinline__ unsigned short f2b(float f) {
  unsigned u = __float_as_uint(f);
  u += 0x7FFFu + ((u >> 16) & 1u);
  return (unsigned short)(u >> 16);
}
__device__ __forceinline__ float b2f(unsigned short h) {
  return __uint_as_float((unsigned)h << 16);
}
__device__ __forceinline__ float2 upk(unsigned u) {
  return make_float2(__uint_as_float(u << 16), __uint_as_float(u & 0xFFFF0000u));
}

// ---------------- graph prep ----------------

__global__ void k_degree(const int* __restrict__ dst, int* __restrict__ degi, int E) {
  int e = blockIdx.x * blockDim.x + threadIdx.x;
  if (e < E) atomicAdd(&degi[dst[e]], 1);
}

__global__ void k_dinv(const int* __restrict__ degi, float* __restrict__ dinv, int n) {
  int i = blockIdx.x * blockDim.x + threadIdx.x;
  if (i < n) dinv[i] = rsqrtf((float)(degi[i] + 1));  // +1 self-loop
}

// 3-phase exclusive scan of deg -> off
__global__ __launch_bounds__(256)
void k_part(const int* __restrict__ deg, int* __restrict__ part, int n) {
  __shared__ int l[256];
  int tid = threadIdx.x, i = blockIdx.x * 256 + tid;
  l[tid] = (i < n) ? deg[i] : 0;
  __syncthreads();
  for (int s = 128; s; s >>= 1) { if (tid < s) l[tid] += l[tid + s]; __syncthreads(); }
  if (!tid) part[blockIdx.x] = l[0];
}

__global__ __launch_bounds__(1024)
void k_scanpart(int* __restrict__ part, int np, int* __restrict__ off_n) {
  __shared__ int l[1024];
  int tid = threadIdx.x;
  int v = (tid < np) ? part[tid] : 0;
  l[tid] = v;
  __syncthreads();
  for (int s = 1; s < 1024; s <<= 1) {
    int t = (tid >= s) ? l[tid - s] : 0;
    __syncthreads();
    l[tid] += t;
    __syncthreads();
  }
  if (tid < np) part[tid] = l[tid] - v;   // exclusive
  if (tid == np - 1) *off_n = l[tid];     // total = E
}

__global__ __launch_bounds__(256)
void k_off(const int* __restrict__ deg, const int* __restrict__ part,
           int* __restrict__ off, int n) {
  __shared__ int l[256];
  int tid = threadIdx.x, i = blockIdx.x * 256 + tid;
  int v = (i < n) ? deg[i] : 0;
  l[tid] = v;
  __syncthreads();
  for (int s = 1; s < 256; s <<= 1) {
    int t = (tid >= s) ? l[tid - s] : 0;
    __syncthreads();
    l[tid] += t;
    __syncthreads();
  }
  if (i < n) off[i] = part[blockIdx.x] + l[tid] - v;
}

__global__ void k_scatter(const int* __restrict__ srcv, const int* __restrict__ dstv,
                          const float* __restrict__ dinv, const int* __restrict__ off,
                          int* __restrict__ cursor, int* __restrict__ csr_src,
                          float* __restrict__ csr_norm, int E) {
  int e = blockIdx.x * blockDim.x + threadIdx.x;
  if (e >= E) return;
  int d = dstv[e];
  int p = atomicAdd(&cursor[d], 1);
  int slot = off[d] + p;
  int s = srcv[e];
  csr_src[slot] = s;
  csr_norm[slot] = dinv[s] * dinv[d];
}

// ---------------- x (f32) -> bf16 ----------------

__global__ void k_cvtx(const float* __restrict__ x, unsigned short* __restrict__ xb,
                       long n4) {
  long t = (long)blockIdx.x * blockDim.x + threadIdx.x;
  if (t >= n4) return;
  float4 v = ((const float4*)x)[t];
  unsigned lo = (unsigned)f2b(v.x) | ((unsigned)f2b(v.y) << 16);
  unsigned hi = (unsigned)f2b(v.z) | ((unsigned)f2b(v.w) << 16);
  ((uint2*)xb)[t] = make_uint2(lo, hi);
}

// ---------------- weight convert + transpose (fp32 [128,128] -> bf16 [128,128]^T) --------

__global__ __launch_bounds__(256)
void k_cvtw(const float* gw0, const float* gw1, const float* gw2,
            const float* wk, const float* wv, const float* wq, const float* ow,
            unsigned short* gwT0, unsigned short* gwT1, unsigned short* gwT2,
            unsigned short* wkvT, unsigned short* wqT, unsigned short* owT) {
  const float* src; unsigned short* dst;
  switch (blockIdx.y) {
    case 0: src = gw0; dst = gwT0; break;
    case 1: src = gw1; dst = gwT1; break;
    case 2: src = gw2; dst = gwT2; break;
    case 3: src = wk;  dst = wkvT; break;
    case 4: src = wv;  dst = wkvT + 128 * 128; break;
    case 5: src = wq;  dst = wqT; break;
    default: src = ow; dst = owT; break;
  }
  int t = blockIdx.x * 256 + threadIdx.x;   // grid.x = 64
  int r = t >> 7, c = t & 127;
  dst[(long)c * 128 + r] = f2b(src[t]);
}

// ---------------- fused GCN layer: out = LN(relu((A_hat @ prev) @ W + b)) + prev -----
// Uses (A_hat H) W == A_hat (H W). Block = 128 thr (2 waves) = 16 nodes.
// Wave w aggregates nodes w*8..w*8+7 (4 rows per b128 gather inst), stages the
// bf16 A-tile in XOR-swizzled LDS, then MFMA vs W^T, epilogue bias/relu/LN/residual.

__global__ __launch_bounds__(128, 6)
void k_gcn_layer(const unsigned short* __restrict__ embp,  // [N][128] bf16
                 const int* __restrict__ off, const int* __restrict__ csr_src,
                 const float* __restrict__ csr_norm, const float* __restrict__ dinv,
                 const unsigned short* __restrict__ wT,    // [128][128] bf16 ^T
                 const float* __restrict__ bias,
                 const float* __restrict__ ln_g, const float* __restrict__ ln_b,
                 unsigned short* __restrict__ embo, int N) {
  __shared__ unsigned a_sw[16 * 64];      // 16 rows x 256B, 16B-chunk XOR swizzle
  __shared__ float lnsum[16][2], lnsq[16][2];

  int tid = threadIdx.x, lane = tid & 63, w = tid >> 6;
  int g = lane >> 4, c16 = lane & 15;
  long n0 = (long)blockIdx.x * 16;

  // ---- phase A: aggregate 8 nodes for this wave
  for (int t = 0; t < 8; ++t) {
    int row = w * 8 + t;
    long node = n0 + row;
    long nc = node < N ? node : N - 1;
    float dn = dinv[nc];
    int s0 = off[nc], s1 = off[nc + 1];
    float acc[8];
    {
      uint4 rs_ = *(const uint4*)&embp[nc * 128 + c16 * 8];
      float wgt = (g == 0) ? dn * dn : 0.f;   // self loop counted once
      float2 f;
      f = upk(rs_.x); acc[0] = f.x * wgt; acc[1] = f.y * wgt;
      f = upk(rs_.y); acc[2] = f.x * wgt; acc[3] = f.y * wgt;
      f = upk(rs_.z); acc[4] = f.x * wgt; acc[5] = f.y * wgt;
      f = upk(rs_.w); acc[6] = f.x * wgt; acc[7] = f.y * wgt;
    }
    for (int i = s0; i < s1; i += 16) {
      int id[4]; float nm[4];
#pragma unroll
      for (int u = 0; u < 4; ++u) {
        int j = i + u * 4 + g;
        int jj = j < s1 ? j : s1 - 1;
        id[u] = csr_src[jj];
        nm[u] = j < s1 ? csr_norm[jj] : 0.f;
      }
      uint4 rv[4];
#pragma unroll
      for (int u = 0; u < 4; ++u)
        rv[u] = *(const uint4*)&embp[(long)id[u] * 128 + c16 * 8];
#pragma unroll
      for (int u = 0; u < 4; ++u) {
        float2 f0 = upk(rv[u].x), f1 = upk(rv[u].y);
        float2 f2 = upk(rv[u].z), f3 = upk(rv[u].w);
        acc[0] += f0.x * nm[u]; acc[1] += f0.y * nm[u];
        acc[2] += f1.x * nm[u]; acc[3] += f1.y * nm[u];
        acc[4] += f2.x * nm[u]; acc[5] += f2.y * nm[u];
        acc[6] += f3.x * nm[u]; acc[7] += f3.y * nm[u];
      }
    }
    // combine the 4 row-groups (lanes differing in bits 4,5)
#pragma unroll
    for (int k = 0; k < 8; ++k) {
      acc[k] += __shfl_xor(acc[k], 16);
      acc[k] += __shfl_xor(acc[k], 32);
    }
    if (g == 0) {
      unsigned* dst = (unsigned*)((char*)a_sw +
                      (row * 256 + ((c16 * 16) ^ ((row & 7) << 4))));
      dst[0] = (unsigned)f2b(acc[0]) | ((unsigned)f2b(acc[1]) << 16);
      dst[1] = (unsigned)f2b(acc[2]) | ((unsigned)f2b(acc[3]) << 16);
      dst[2] = (unsigned)f2b(acc[4]) | ((unsigned)f2b(acc[5]) << 16);
      dst[3] = (unsigned)f2b(acc[6]) | ((unsigned)f2b(acc[7]) << 16);
    }
  }
  __syncthreads();

  // ---- phase B: [16,128] = A @ wT^T ; this wave: cols w*64..+64
  int lo = lane & 15, hi = lane >> 4;
  int cb0 = w * 64;
  f32x4 acc2[4] = {};
#pragma unroll
  for (int ks = 0; ks < 4; ++ks) {
    int k0 = ks * 32 + hi * 8;
    bf16x8 a = *(const bf16x8*)((char*)a_sw + lo * 256 + ((k0 * 2) ^ ((lo & 7) << 4)));
#pragma unroll
    for (int cf = 0; cf < 4; ++cf) {
      bf16x8 b = *(const bf16x8*)&wT[(long)(cb0 + cf * 16 + lo) * 128 + k0];
      acc2[cf] = __builtin_amdgcn_mfma_f32_16x16x32_bf16(a, b, acc2[cf], 0, 0, 0);
    }
  }

  // ---- phase C: bias + relu + LN + residual + store
  float vreg[4][4];   // [cf][j] ; row = hi*4+j, col = cb0+cf*16+lo
#pragma unroll
  for (int j = 0; j < 4; ++j) {
    float s = 0.f, q = 0.f;
#pragma unroll
    for (int cf = 0; cf < 4; ++cf) {
      int col = cb0 + cf * 16 + lo;
      float v = fmaxf(acc2[cf][j] + bias[col], 0.f);
      vreg[cf][j] = v;
      s += v; q += v * v;
    }
#pragma unroll
    for (int m = 1; m < 16; m <<= 1) { s += __shfl_xor(s, m); q += __shfl_xor(q, m); }
    if (lo == 0) { lnsum[hi * 4 + j][w] = s; lnsq[hi * 4 + j][w] = q; }
  }
  __syncthreads();
#pragma unroll
  for (int j = 0; j < 4; ++j) {
    int row = hi * 4 + j;
    float sum = lnsum[row][0] + lnsum[row][1];
    float sq  = lnsq[row][0] + lnsq[row][1];
    float mu = sum * (1.f / 128.f);
    float var = sq * (1.f / 128.f) - mu * mu;
    float rs = rsqrtf(var + 1e-5f);
    long gr = n0 + row;
    if (gr < N) {
#pragma unroll
      for (int cf = 0; cf < 4; ++cf) {
        int col = cb0 + cf * 16 + lo;
        float z = (vreg[cf][j] - mu) * rs * ln_g[col] + ln_b[col]
                  + b2f(embp[gr * 128 + col]);
        embo[gr * 128 + col] = f2b(z);
      }
    }
  }
}

// ---------------- fused: kv-proj + q-proj + attention + LN + out-proj ----------------
// Block = 256 thr (4 waves) handles 16 nodes. emb layout [3][N][128] bf16.

__global__ __launch_bounds__(256)
void k_attn_fused(const unsigned short* __restrict__ emb,   // [3][N][128]
                  const unsigned short* __restrict__ wkvT,  // [256][128]
                  const unsigned short* __restrict__ wqT,   // [128][128]
                  const unsigned short* __restrict__ owT,   // [128][128]
                  const float* __restrict__ ln_g, const float* __restrict__ ln_b,
                  const float* __restrict__ out_b,
                  float* __restrict__ zout, int N) {
  __shared__ unsigned short kvl[48 * 256];  // row = l*16+node : [K | V]
  __shared__ unsigned short ql[16 * 128];
  __shared__ unsigned short zl[16 * 128];   // XOR-swizzled

  int tid = threadIdx.x, lane = tid & 63, w = tid >> 6;
  int lo = lane & 15, hi = lane >> 4;
  long n0 = (long)blockIdx.x * 16;
  long nr = n0 + lo; if (nr >= N) nr = N - 1;

  // ---- phase 1: KV[48,256]
  {
    int cb0 = w * 64;
    f32x4 acc[3][4] = {};
#pragma unroll
    for (int ks = 0; ks < 4; ++ks) {
      int k0 = ks * 32 + hi * 8;
      bf16x8 a[3];
#pragma unroll
      for (int l = 0; l < 3; ++l)
        a[l] = *(const bf16x8*)&emb[((long)l * N + nr) * 128 + k0];
#pragma unroll
      for (int cf = 0; cf < 4; ++cf) {
        bf16x8 b = *(const bf16x8*)&wkvT[(long)(cb0 + cf * 16 + lo) * 128 + k0];
#pragma unroll
        for (int l = 0; l < 3; ++l)
          acc[l][cf] = __builtin_amdgcn_mfma_f32_16x16x32_bf16(a[l], b, acc[l][cf], 0, 0, 0);
      }
    }
#pragma unroll
    for (int l = 0; l < 3; ++l)
#pragma unroll
      for (int cf = 0; cf < 4; ++cf)
#pragma unroll
        for (int j = 0; j < 4; ++j)
          kvl[(l * 16 + hi * 4 + j) * 256 + cb0 + cf * 16 + lo] = f2b(acc[l][cf][j]);
  }

  // ---- phase 2: Q[16,128] (layer 2)
  {
    int cq0 = w * 32;
    f32x4 aq[2] = {};
#pragma unroll
    for (int ks = 0; ks < 4; ++ks) {
      int k0 = ks * 32 + hi * 8;
      bf16x8 a = *(const bf16x8*)&emb[(2L * N + nr) * 128 + k0];
#pragma unroll
      for (int cf = 0; cf < 2; ++cf) {
        bf16x8 b = *(const bf16x8*)&wqT[(long)(cq0 + cf * 16 + lo) * 128 + k0];
        aq[cf] = __builtin_amdgcn_mfma_f32_16x16x32_bf16(a, b, aq[cf], 0, 0, 0);
      }
    }
#pragma unroll
    for (int cf = 0; cf < 2; ++cf)
#pragma unroll
      for (int j = 0; j < 4; ++j)
        ql[(hi * 4 + j) * 128 + cq0 + cf * 16 + lo] = f2b(aq[cf][j]);
  }
  __syncthreads();

  // ---- phase 3: attention + LN ; wave handles nodes w*4 .. w*4+3
  {
    const unsigned* kvu = (const unsigned*)kvl;
    const unsigned* qu  = (const unsigned*)ql;
    int c = lane * 2;
    float gx = ln_g[c], gy = ln_g[c + 1], bx = ln_b[c], by = ln_b[c + 1];
#pragma unroll
    for (int it = 0; it < 4; ++it) {
      int node = w * 4 + it;
      float2 q = upk(qu[node * 64 + lane]);
      float s[3], vx[3], vy[3];
#pragma unroll
      for (int m = 0; m < 3; ++m) {
        int row = m * 16 + node;
        float2 k = upk(kvu[row * 128 + lane]);
        float2 v = upk(kvu[row * 128 + 64 + lane]);
        float p = q.x * k.x + q.y * k.y;
        p += __shfl_xor(p, 1); p += __shfl_xor(p, 2); p += __shfl_xor(p, 4);
        s[m] = p * 0.25f;   // /sqrt(16)
        vx[m] = v.x; vy[m] = v.y;
      }
      float mx = fmaxf(s[0], fmaxf(s[1], s[2]));
      float e0 = __expf(s[0] - mx), e1 = __expf(s[1] - mx), e2 = __expf(s[2] - mx);
      float inv = 1.f / (e0 + e1 + e2);
      float cx = (e0 * vx[0] + e1 * vx[1] + e2 * vx[2]) * inv;
      float cy = (e0 * vy[0] + e1 * vy[1] + e2 * vy[2]) * inv;
      float sum = cx + cy, sq = cx * cx + cy * cy;
#pragma unroll
      for (int m = 1; m < 64; m <<= 1) { sum += __shfl_xor(sum, m); sq += __shfl_xor(sq, m); }
      float mu = sum * (1.f / 128.f);
      float var = sq * (1.f / 128.f) - mu * mu;
      float rs = rsqrtf(var + 1e-5f);
      unsigned pk = (unsigned)f2b((cx - mu) * rs * gx + bx) |
                    ((unsigned)f2b((cy - mu) * rs * gy + by) << 16);
      *(unsigned*)((char*)zl + node * 256 + ((lane * 4) ^ ((node & 7) << 4))) = pk;
    }
  }
  __syncthreads();

  // ---- phase 4: zout[16,128] = z @ owT^T + out_b
  {
    int co0 = w * 32;
    f32x4 ao[2] = {};
#pragma unroll
    for (int ks = 0; ks < 4; ++ks) {
      int k0 = ks * 32 + hi * 8;
      bf16x8 a = *(const bf16x8*)((const char*)zl + lo * 256 + (((k0 * 2) ^ ((lo & 7) << 4))));
#pragma unroll
      for (int cf = 0; cf < 2; ++cf) {
        bf16x8 b = *(const bf16x8*)&owT[(long)(co0 + cf * 16 + lo) * 128 + k0];
        ao[cf] = __builtin_amdgcn_mfma_f32_16x16x32_bf16(a, b, ao[cf], 0, 0, 0);
      }
    }
#pragma unroll
    for (int cf = 0; cf < 2; ++cf)
#pragma unroll
      for (int j = 0; j < 4; ++j) {
        long gn = n0 + hi * 4 + j;
        int col = co0 + cf * 16 + lo;
        if (gn < N) zout[gn * 128 + col] = ao[cf][j] + out_b[col];
      }
  }
}

// ---------------- gather rows (fp32 zout); blockIdx.y = id set ----------------

__global__ void k_gather4(const float* __restrict__ zout,
                          const int* __restrict__ ids0, const int* __restrict__ ids1,
                          const int* __restrict__ ids2, const int* __restrict__ ids3,
                          float* __restrict__ outp, int rows) {
  int t = blockIdx.x * blockDim.x + threadIdx.x;  // one float4 per thread
  if (t >= rows * 32) return;
  int s = blockIdx.y;
  const int* ids = (s == 0) ? ids0 : (s == 1) ? ids1 : (s == 2) ? ids2 : ids3;
  int row = t >> 5, c4 = t & 31;
  long id = ids[row];
  ((float4*)outp)[((long)s * rows + row) * 32 + c4] = ((const float4*)zout)[id * 32 + c4];
}

// ---------------- host ----------------

extern "C" void kernel_launch(void* const* d_in, const int* in_sizes, int n_in,
                              void* d_out, int out_size, void* d_ws, size_t ws_size,
                              hipStream_t stream) {
  const float* x = (const float*)d_in[0];
  const int* ei = (const int*)d_in[1];
  const int* ids[4] = {(const int*)d_in[2], (const int*)d_in[3],
                       (const int*)d_in[4], (const int*)d_in[5]};
  const float* gw[3] = {(const float*)d_in[7], (const float*)d_in[9], (const float*)d_in[11]};
  const float* gb[3] = {(const float*)d_in[8], (const float*)d_in[10], (const float*)d_in[12]};
  const float* wq = (const float*)d_in[13];
  const float* wk = (const float*)d_in[14];
  const float* wv = (const float*)d_in[15];
  const float* ln_g = (const float*)d_in[16];
  const float* ln_b = (const float*)d_in[17];
  const float* out_w = (const float*)d_in[18];
  const float* out_b = (const float*)d_in[19];

  const int N = in_sizes[0] / 128;
  const int E = in_sizes[1] / 2;
  const int P = in_sizes[2];

  char* w = (char*)d_ws;
  size_t o = 0;
  auto take = [&](size_t bytes) -> void* {
    void* p = w + o;
    o = (o + bytes + 255) & ~(size_t)255;
    return p;
  };
  int*   degi    = (int*)take((size_t)N * 4);
  int*   off     = (int*)take((size_t)(N + 1) * 4);
  int*   cursor  = (int*)take((size_t)N * 4);
  int*   part    = (int*)take(1024 * 4);
  float* dinv    = (float*)take((size_t)N * 4);
  int*   csr_src = (int*)take((size_t)E * 4);
  float* csr_nrm = (float*)take((size_t)E * 4);
  unsigned short* gwT0 = (unsigned short*)take(128 * 128 * 2);
  unsigned short* gwT1 = (unsigned short*)take(128 * 128 * 2);
  unsigned short* gwT2 = (unsigned short*)take(128 * 128 * 2);
  unsigned short* wkvT = (unsigned short*)take(256 * 128 * 2);
  unsigned short* wqT  = (unsigned short*)take(128 * 128 * 2);
  unsigned short* owT  = (unsigned short*)take(128 * 128 * 2);
  unsigned short* xbf  = (unsigned short*)take((size_t)N * 128 * 2);
  unsigned short* emball = (unsigned short*)take((size_t)3 * N * 128 * 2);
  float* zout = (float*)take((size_t)N * 128 * 4);
  (void)ws_size; (void)n_in; (void)out_size;

  hipMemsetAsync(degi, 0, (size_t)N * 4, stream);
  hipMemsetAsync(cursor, 0, (size_t)N * 4, stream);

  int eb = (E + 255) / 256;
  int nb = (N + 255) / 256;
  k_degree<<<eb, 256, 0, stream>>>(ei + E, degi, E);
  k_dinv<<<nb, 256, 0, stream>>>(degi, dinv, N);
  k_part<<<nb, 256, 0, stream>>>(degi, part, N);
  k_scanpart<<<1, 1024, 0, stream>>>(part, nb, off + N);
  k_off<<<nb, 256, 0, stream>>>(degi, part, off, N);
  k_scatter<<<eb, 256, 0, stream>>>(ei, ei + E, dinv, off, cursor, csr_src, csr_nrm, E);
  k_cvtw<<<dim3(64, 7), 256, 0, stream>>>(gw[0], gw[1], gw[2], wk, wv, wq, out_w,
                                          gwT0, gwT1, gwT2, wkvT, wqT, owT);
  long n4 = (long)N * 32;
  k_cvtx<<<(int)((n4 + 255) / 256), 256, 0, stream>>>(x, xbf, n4);

  unsigned short* gwT[3] = {gwT0, gwT1, gwT2};
  int lgrid = (N + 15) / 16;
  const unsigned short* prev = xbf;
  for (int l = 0; l < 3; ++l) {
    unsigned short* outp = emball + (size_t)l * N * 128;
    k_gcn_layer<<<lgrid, 128, 0, stream>>>(prev, off, csr_src, csr_nrm, dinv,
                                           gwT[l], gb[l], ln_g, ln_b, outp, N);
    prev = outp;
  }

  // fused kv/q projections + attention + LN + out-proj
  k_attn_fused<<<(N + 15) / 16, 256, 0, stream>>>(emball, wkvT, wqT, owT,
                                                  ln_g, ln_b, out_b, zout, N);

  float* outf = (float*)d_out;
  int gb2 = (P * 32 + 255) / 256;
  k_gather4<<<dim3(gb2, 4), 256, 0, stream>>>(zout, ids[0], ids[1], ids[2], ids[3],
                                              outf, P);
}